// Round 4
// baseline (4186.737 us; speedup 1.0000x reference)
//
#include <hip/hip_runtime.h>
#include <hip/hip_bf16.h>
#include <math.h>

#define B_ 4
#define D_ 512
#define T_ 1024
#define H_ 8
#define FFD 2048

__device__ inline float sigm(float x){ return 1.f/(1.f+expf(-x)); }
__device__ inline float gelu_exact(float x){ return 0.5f*x*(1.f+erff(x*0.70710678118654752440f)); }

// ---- transpose x (f32 [B,D,T]) -> s (f32 [B,T,D])
__global__ void k_transpose_in(const float* __restrict__ x, float* __restrict__ s) {
  __shared__ float tile[32][33];
  int b = blockIdx.z;
  int d0 = blockIdx.y * 32;
  int t0 = blockIdx.x * 32;
  int c = threadIdx.x & 31, r = threadIdx.x >> 5; // r 0..7
  for (int rr = r; rr < 32; rr += 8)
    tile[rr][c] = x[((size_t)(b*D_ + d0 + rr))*T_ + t0 + c];
  __syncthreads();
  for (int rr = r; rr < 32; rr += 8)
    s[((size_t)(b*T_ + t0 + rr))*D_ + d0 + c] = tile[c][rr];
}

// ---- s (f32 [B,T,D]) -> out (f32 [B,D,T])
__global__ void k_transpose_out(const float* __restrict__ s, float* __restrict__ o) {
  __shared__ float tile[32][33];
  int b = blockIdx.z;
  int t0 = blockIdx.y * 32;
  int d0 = blockIdx.x * 32;
  int c = threadIdx.x & 31, r = threadIdx.x >> 5;
  for (int rr = r; rr < 32; rr += 8)
    tile[rr][c] = s[((size_t)(b*T_ + t0 + rr))*D_ + d0 + c];
  __syncthreads();
  for (int rr = r; rr < 32; rr += 8)
    o[((size_t)(b*D_ + d0 + rr))*T_ + t0 + c] = tile[c][rr];
}

// ---- generic tiled GEMM: C[M,N] = epi(A[M,K] f32 @ W[K,N] f32 + bias)
// act: 0 none, 1 gelu.  res: C = res + scale*val if res != null
__global__ __launch_bounds__(256) void k_gemm(
    const float* __restrict__ A, const float* __restrict__ W, const float* __restrict__ bias,
    const float* __restrict__ res, float scale, float* __restrict__ C,
    int M, int N, int K, int act)
{
  __shared__ float As[16][65];
  __shared__ float Ws[16][64];
  int tid = threadIdx.x;
  int m0 = blockIdx.y << 6, n0 = blockIdx.x << 6;
  int ty = tid >> 4, tx = tid & 15;
  int ar = tid >> 2, ac4 = (tid & 3) << 2;
  int wr = tid >> 4, wc4 = (tid & 15) << 2;
  float acc[4][4] = {{0.f}};
  for (int k0 = 0; k0 < K; k0 += 16) {
    float4 av = *reinterpret_cast<const float4*>(A + (size_t)(m0+ar)*K + k0 + ac4);
    As[ac4+0][ar]=av.x; As[ac4+1][ar]=av.y; As[ac4+2][ar]=av.z; As[ac4+3][ar]=av.w;
    float4 wv = *reinterpret_cast<const float4*>(W + (size_t)(k0+wr)*N + n0 + wc4);
    Ws[wr][wc4+0]=wv.x; Ws[wr][wc4+1]=wv.y; Ws[wr][wc4+2]=wv.z; Ws[wr][wc4+3]=wv.w;
    __syncthreads();
    #pragma unroll
    for (int k = 0; k < 16; ++k) {
      float a0=As[k][(ty<<2)+0],a1=As[k][(ty<<2)+1],a2=As[k][(ty<<2)+2],a3=As[k][(ty<<2)+3];
      float b0=Ws[k][(tx<<2)+0],b1=Ws[k][(tx<<2)+1],b2=Ws[k][(tx<<2)+2],b3=Ws[k][(tx<<2)+3];
      acc[0][0]+=a0*b0; acc[0][1]+=a0*b1; acc[0][2]+=a0*b2; acc[0][3]+=a0*b3;
      acc[1][0]+=a1*b0; acc[1][1]+=a1*b1; acc[1][2]+=a1*b2; acc[1][3]+=a1*b3;
      acc[2][0]+=a2*b0; acc[2][1]+=a2*b1; acc[2][2]+=a2*b2; acc[2][3]+=a2*b3;
      acc[3][0]+=a3*b0; acc[3][1]+=a3*b1; acc[3][2]+=a3*b2; acc[3][3]+=a3*b3;
    }
    __syncthreads();
  }
  #pragma unroll
  for (int i=0;i<4;++i)
    #pragma unroll
    for (int j=0;j<4;++j) {
      int m = m0 + (ty<<2) + i, n = n0 + (tx<<2) + j;
      float v = acc[i][j] + bias[n];
      if (act==1) v = gelu_exact(v);
      size_t off = (size_t)m*N + n;
      C[off] = res ? res[off] + scale*v : v;
    }
}

// ---- split qkv [B*T,1536] -> q,k,v [B,H,T,64]
__global__ void k_repack_qkv(const float* __restrict__ qkv, float* __restrict__ q,
                             float* __restrict__ k, float* __restrict__ v) {
  size_t idx = (size_t)blockIdx.x*256 + threadIdx.x; // B*H*T*64
  int dh = idx & 63;
  int t = (idx >> 6) & (T_-1);
  int h = (idx >> 16) & (H_-1);
  int b = (int)(idx >> 19);
  size_t src = ((size_t)(b*T_ + t))*1536 + h*64 + dh;
  q[idx] = qkv[src];
  k[idx] = qkv[src + 512];
  v[idx] = qkv[src + 1024];
}

// ---- WavLM relative-position buckets [T,T]
__global__ void k_bucket(int* __restrict__ bucket) {
  int idx = blockIdx.x*256 + threadIdx.x;
  int t = idx >> 10, s = idx & 1023;
  int rel = s - t;
  int sign = rel >= 0 ? 1 : 0;
  int a = rel >= 0 ? rel : -rel;
  int bkt;
  if (a < 80) bkt = a;
  else {
    float lr = logf((float)a / 80.f) / 2.30258509299404568402f;
    int lp = 80 + (int)(lr * 80.f);
    bkt = lp < 159 ? lp : 159;
  }
  bucket[idx] = bkt + sign*160;
}

// ---- attention: one block (256 thr) per (b,h,t)
__global__ __launch_bounds__(256) void k_attn(
    const float* __restrict__ q, const float* __restrict__ k, const float* __restrict__ v,
    const int* __restrict__ bucket, const float* __restrict__ rel_embed,
    const float* __restrict__ gate_u, const float* __restrict__ gate_w, const float* __restrict__ gate_scale,
    float* __restrict__ attn_out)
{
  __shared__ float qs[64];
  __shared__ float p[1024];
  __shared__ float red[256];
  __shared__ float sh_coef;
  int blk = blockIdx.x;
  int t = blk & (T_-1);
  int h = (blk >> 10) & (H_-1);
  int b = blk >> 13;
  int tid = threadIdx.x;
  const float* qrow = q + ((size_t)((b*H_+h)*T_ + t))*64;
  if (tid < 64) qs[tid] = qrow[tid];
  __syncthreads();
  if (tid < 64) {
    float vu = qs[tid]*gate_u[h*64+tid];
    float vw = qs[tid]*gate_w[h*64+tid];
    #pragma unroll
    for (int off=32; off; off>>=1){ vu += __shfl_down(vu,off); vw += __shfl_down(vw,off); }
    if (tid==0) {
      float gu = sigm(vu), gw = sigm(vw);
      sh_coef = 1.f + gu + (1.f-gu)*gate_scale[h]*gw;
    }
  }
  __syncthreads();
  float coef = sh_coef;
  const float* kb = k + (size_t)(b*H_+h)*T_*64;
  const int* brow = bucket + (size_t)t*T_;
  float lmax = -1e30f;
  for (int s = tid; s < T_; s += 256) {
    const float* kr = kb + (size_t)s*64;
    float acc = 0.f;
    #pragma unroll
    for (int d0=0; d0<64; d0+=4){
      float4 kv4 = *reinterpret_cast<const float4*>(kr+d0);
      acc += qs[d0]*kv4.x + qs[d0+1]*kv4.y + qs[d0+2]*kv4.z + qs[d0+3]*kv4.w;
    }
    // scores*4/32 = q.k/8 ; pre-bias row-max subtraction is softmax-invariant
    float sc = acc*0.125f + coef*rel_embed[brow[s]*H_ + h];
    p[s] = sc;
    lmax = fmaxf(lmax, sc);
  }
  red[tid] = lmax; __syncthreads();
  for (int off=128; off; off>>=1){ if (tid<off) red[tid]=fmaxf(red[tid],red[tid+off]); __syncthreads(); }
  float m = red[0]; __syncthreads();
  float lsum = 0.f;
  for (int s = tid; s < T_; s += 256){ float e = expf(p[s]-m); p[s]=e; lsum+=e; }
  red[tid] = lsum; __syncthreads();
  for (int off=128; off; off>>=1){ if (tid<off) red[tid]+=red[tid+off]; __syncthreads(); }
  float den = red[0];
  __syncthreads();
  int d = tid & 63, grp = tid >> 6;
  const float* vb = v + (size_t)(b*H_+h)*T_*64;
  float acc = 0.f;
  for (int s = grp*256; s < grp*256+256; ++s) acc += p[s]*vb[(size_t)s*64 + d];
  red[tid] = acc; __syncthreads();
  if (tid < 64) {
    float r0 = red[tid]+red[tid+64]+red[tid+128]+red[tid+192];
    attn_out[((size_t)(b*T_+t))*512 + h*64 + tid] = r0/den;
  }
}

// ---- GroupNorm(1,C) stats per batch over [T*D] elems
__global__ __launch_bounds__(256) void k_gn_stats(const float* __restrict__ x, float* __restrict__ stats) {
  int b = blockIdx.x;
  const float* xb = x + (size_t)b*D_*T_;
  float s=0.f, s2=0.f;
  for (int i = threadIdx.x; i < D_*T_; i += 256){ float v = xb[i]; s += v; s2 += v*v; }
  __shared__ float rs[256], rq[256];
  rs[threadIdx.x]=s; rq[threadIdx.x]=s2; __syncthreads();
  for (int off=128; off; off>>=1){
    if (threadIdx.x<off){ rs[threadIdx.x]+=rs[threadIdx.x+off]; rq[threadIdx.x]+=rq[threadIdx.x+off]; }
    __syncthreads();
  }
  if (threadIdx.x==0){
    float n = (float)(D_*T_);
    float mean = rs[0]/n;
    float var = rq[0]/n - mean*mean;
    stats[b*2] = mean;
    stats[b*2+1] = rsqrtf(var + 1e-5f);
  }
}

__global__ void k_gn_apply(const float* __restrict__ x, const float* __restrict__ stats,
                           const float* __restrict__ g, const float* __restrict__ bta,
                           float* __restrict__ o, int silu_flag)
{
  size_t idx = (size_t)blockIdx.x*256 + threadIdx.x; // B*T*D
  int d = idx & (D_-1);
  int b = (int)(idx >> 19);
  float mean = stats[b*2], istd = stats[b*2+1];
  float v = (x[idx]-mean)*istd*g[d] + bta[d];
  if (silu_flag) v = v*sigm(v);
  o[idx] = v;
}

__global__ void k_glu(const float* __restrict__ h2, float* __restrict__ g) {
  size_t idx = (size_t)blockIdx.x*256 + threadIdx.x; // B*T*512
  int d = idx & 511;
  size_t row = idx >> 9;
  float a = h2[row*1024 + d], bb = h2[row*1024 + 512 + d];
  g[idx] = a * sigm(bb);
}

__global__ void k_dwconv(const float* __restrict__ g, const float* __restrict__ w,
                         const float* __restrict__ bias, float* __restrict__ o)
{
  size_t idx = (size_t)blockIdx.x*256 + threadIdx.x; // B*T*D
  int d = idx & 511;
  int t = (int)((idx >> 9) & 1023);
  int b = (int)(idx >> 19);
  float acc = bias[d];
  const float* gb = g + (size_t)b*T_*D_;
  #pragma unroll
  for (int kk=0; kk<31; ++kk){
    int tt = t + kk - 15;
    if (tt >= 0 && tt < T_) acc += gb[(size_t)tt*D_ + d]*w[d*31+kk];
  }
  o[idx] = acc;
}

extern "C" void kernel_launch(void* const* d_in, const int* in_sizes, int n_in,
                              void* d_out, int out_size, void* d_ws, size_t ws_size,
                              hipStream_t stream)
{
  const float* x      = (const float*)d_in[0];
  const float* ff1_w1 = (const float*)d_in[1];
  const float* ff1_b1 = (const float*)d_in[2];
  const float* ff1_w2 = (const float*)d_in[3];
  const float* ff1_b2 = (const float*)d_in[4];
  const float* qkv_w  = (const float*)d_in[5];
  const float* qkv_b  = (const float*)d_in[6];
  const float* out_w  = (const float*)d_in[7];
  const float* out_b  = (const float*)d_in[8];
  const float* gn1_g  = (const float*)d_in[9];
  const float* gn1_b  = (const float*)d_in[10];
  const float* pw1_w  = (const float*)d_in[11];
  const float* pw1_b  = (const float*)d_in[12];
  const float* dw_w   = (const float*)d_in[13];
  const float* dw_b   = (const float*)d_in[14];
  const float* gn2_g  = (const float*)d_in[15];
  const float* gn2_b  = (const float*)d_in[16];
  const float* pw2_w  = (const float*)d_in[17];
  const float* pw2_b  = (const float*)d_in[18];
  const float* ff2_w1 = (const float*)d_in[19];
  const float* ff2_b1 = (const float*)d_in[20];
  const float* ff2_w2 = (const float*)d_in[21];
  const float* ff2_b2 = (const float*)d_in[22];
  const float* rel_embed = (const float*)d_in[23];
  const float* gate_u = (const float*)d_in[24];
  const float* gate_w = (const float*)d_in[25];
  const float* gate_scale = (const float*)d_in[26];

  char* ws = (char*)d_ws;
  const size_t MB = (size_t)1<<20;
  float* S   = (float*)(ws + 0*MB);
  float* S2  = (float*)(ws + 8*MB);
  float* BIG = (float*)(ws + 16*MB);   // 32 MiB: holds up to [4096, 2048] f32
  float* Q   = (float*)(ws + 48*MB);
  float* Kb  = (float*)(ws + 56*MB);
  float* V   = (float*)(ws + 64*MB);
  float* AUX = (float*)(ws + 72*MB);
  int*   BKT = (int*)  (ws + 80*MB);
  float* ST1 = (float*)(ws + 84*MB);
  float* ST2 = (float*)(ws + 84*MB + 4096);

  int M = B_*T_;
  dim3 blk(256);

  k_transpose_in<<<dim3(T_/32, D_/32, B_), blk, 0, stream>>>(x, S2);
  // FFN1
  k_gemm<<<dim3(FFD/64, M/64), blk, 0, stream>>>(S2, ff1_w1, ff1_b1, nullptr, 0.f, BIG, M, FFD, D_, 1);
  k_gemm<<<dim3(D_/64, M/64), blk, 0, stream>>>(BIG, ff1_w2, ff1_b2, S2, 0.5f, S, M, D_, FFD, 0);
  // QKV
  k_gemm<<<dim3(1536/64, M/64), blk, 0, stream>>>(S, qkv_w, qkv_b, nullptr, 0.f, BIG, M, 1536, D_, 0);
  k_repack_qkv<<<dim3((B_*H_*T_*64)/256), blk, 0, stream>>>(BIG, Q, Kb, V);
  k_bucket<<<dim3((T_*T_)/256), blk, 0, stream>>>(BKT);
  k_attn<<<dim3(B_*H_*T_), blk, 0, stream>>>(Q, Kb, V, BKT, rel_embed, gate_u, gate_w, gate_scale, AUX);
  // out proj + residual
  k_gemm<<<dim3(D_/64, M/64), blk, 0, stream>>>(AUX, out_w, out_b, S, 1.f, S2, M, D_, D_, 0);
  // conv module
  k_gn_stats<<<dim3(B_), blk, 0, stream>>>(S2, ST1);
  k_gn_apply<<<dim3((M*D_)/256), blk, 0, stream>>>(S2, ST1, gn1_g, gn1_b, AUX, 0);
  k_gemm<<<dim3(1024/64, M/64), blk, 0, stream>>>(AUX, pw1_w, pw1_b, nullptr, 0.f, BIG, M, 1024, D_, 0);
  k_glu<<<dim3((M*512)/256), blk, 0, stream>>>(BIG, AUX);
  k_dwconv<<<dim3((M*D_)/256), blk, 0, stream>>>(AUX, dw_w, dw_b, Q);
  k_gn_stats<<<dim3(B_), blk, 0, stream>>>(Q, ST2);
  k_gn_apply<<<dim3((M*D_)/256), blk, 0, stream>>>(Q, ST2, gn2_g, gn2_b, Kb, 1);
  k_gemm<<<dim3(D_/64, M/64), blk, 0, stream>>>(Kb, pw2_w, pw2_b, S2, 1.f, V, M, D_, D_, 0);
  // FFN2
  k_gemm<<<dim3(FFD/64, M/64), blk, 0, stream>>>(V, ff2_w1, ff2_b1, nullptr, 0.f, BIG, M, FFD, D_, 1);
  k_gemm<<<dim3(D_/64, M/64), blk, 0, stream>>>(BIG, ff2_w2, ff2_b2, V, 0.5f, S, M, D_, FFD, 0);
  k_transpose_out<<<dim3(D_/32, T_/32, B_), blk, 0, stream>>>(S, (float*)d_out);
}

// Round 6
// 868.087 us; speedup vs baseline: 4.8229x; 4.8229x over previous
//
#include <hip/hip_runtime.h>
#include <hip/hip_bf16.h>
#include <math.h>

#define B_ 4
#define D_ 512
#define T_ 1024
#define H_ 8
#define FFD 2048

typedef unsigned short u16;
typedef short s16x8 __attribute__((ext_vector_type(8)));
typedef float f32x4 __attribute__((ext_vector_type(4)));

__device__ inline float sigm(float x){ return 1.f/(1.f+expf(-x)); }
__device__ inline float gelu_exact(float x){ return 0.5f*x*(1.f+erff(x*0.70710678118654752440f)); }
__device__ inline u16 f2b(float f){
  __hip_bfloat16 h = __float2bfloat16(f);
  return *reinterpret_cast<u16*>(&h);
}

__device__ inline void gl_lds16(const void* g, void* l) {
  __builtin_amdgcn_global_load_lds(
      (const __attribute__((address_space(1))) void*)g,
      (__attribute__((address_space(3))) void*)l, 16, 0, 0);
}

// ---- weight transpose+cast: W f32 [K][N] -> Wt bf16 [N][K]
__global__ __launch_bounds__(256) void k_wt(const float* __restrict__ w, u16* __restrict__ wt, int K, int N) {
  __shared__ float tile[32][33];
  int n0 = blockIdx.x*32, k0 = blockIdx.y*32;
  int c = threadIdx.x & 31, r = threadIdx.x >> 5;
  for (int rr = r; rr < 32; rr += 8)
    tile[rr][c] = w[(size_t)(k0+rr)*N + n0 + c];
  __syncthreads();
  for (int rr = r; rr < 32; rr += 8)
    wt[(size_t)(n0+rr)*K + k0 + c] = f2b(tile[c][rr]);
}

// ---- x f32 [B,D,T] -> s0 f32 [B,T,D] + bf16 copy
__global__ __launch_bounds__(256) void k_xin(const float* __restrict__ x, float* __restrict__ sf, u16* __restrict__ sb) {
  __shared__ float tile[32][33];
  int b = blockIdx.z;
  int d0 = blockIdx.y * 32;
  int t0 = blockIdx.x * 32;
  int c = threadIdx.x & 31, r = threadIdx.x >> 5;
  for (int rr = r; rr < 32; rr += 8)
    tile[rr][c] = x[((size_t)(b*D_ + d0 + rr))*T_ + t0 + c];
  __syncthreads();
  for (int rr = r; rr < 32; rr += 8) {
    float v = tile[c][rr];
    size_t o = ((size_t)(b*T_ + t0 + rr))*D_ + d0 + c;
    sf[o] = v; sb[o] = f2b(v);
  }
}

// ---- final: s f32 [B,T,D] -> out f32 [B,D,T]
__global__ __launch_bounds__(256) void k_transpose_out(const float* __restrict__ s, float* __restrict__ o) {
  __shared__ float tile[32][33];
  int b = blockIdx.z;
  int t0 = blockIdx.y * 32;
  int d0 = blockIdx.x * 32;
  int c = threadIdx.x & 31, r = threadIdx.x >> 5;
  for (int rr = r; rr < 32; rr += 8)
    tile[rr][c] = s[((size_t)(b*T_ + t0 + rr))*D_ + d0 + c];
  __syncthreads();
  for (int rr = r; rr < 32; rr += 8)
    o[((size_t)(b*D_ + d0 + rr))*T_ + t0 + c] = tile[c][rr];
}

// ---- MFMA GEMM: C[M,N] = epi(A[M,K]bf16 @ Wt[N,K]bf16^T + bias)
// 128x128 tile, BK=64, 4 waves (2x2), each wave 64x64 via 4x4 frags of 16x16x32.
// LDS linear [128][64] bf16, (r&7) 16B-chunk XOR swizzle (pre-swizzled source).
__global__ __launch_bounds__(256) void k_gemm_mfma(
    const u16* __restrict__ A, const u16* __restrict__ Wt,
    const float* __restrict__ bias, const float* __restrict__ res, float rscale,
    float* __restrict__ outf, u16* __restrict__ outb,
    float* __restrict__ qd, float* __restrict__ kd, float* __restrict__ vd,
    int M, int N, int K, int act)
{
  __shared__ u16 Ab[128*64];
  __shared__ u16 Bb[128*64];
  int tid = threadIdx.x;
  int w = tid >> 6, lane = tid & 63;
  int lr = lane & 15, lk = lane >> 4;
  int wm = w >> 1, wn = w & 1;
  int m0 = blockIdx.y * 128, n0 = blockIdx.x * 128;
  f32x4 acc[4][4] = {};

  // per-lane source slot for staging (16 rounds of 64 lanes over 1024 slots)
  for (int kt = 0; kt < K; kt += 64) {
    #pragma unroll
    for (int i = 0; i < 4; ++i) {
      int slot = (w*4 + i)*64 + lane;       // 16B-slot 0..1023
      int r = slot >> 3, sc = slot & 7;
      int cc = sc ^ (r & 7);                // pre-swizzled source chunk
      gl_lds16(A  + (size_t)(m0 + r)*K + kt + cc*8, (char*)Ab + (size_t)(w*4+i)*1024);
      gl_lds16(Wt + (size_t)(n0 + r)*K + kt + cc*8, (char*)Bb + (size_t)(w*4+i)*1024);
    }
    __syncthreads();
    #pragma unroll
    for (int ks = 0; ks < 2; ++ks) {
      s16x8 af[4], bfv[4];
      #pragma unroll
      for (int m = 0; m < 4; ++m) {
        int r = wm*64 + m*16 + lr;
        int sl = (ks*4 + lk) ^ (r & 7);
        af[m] = *(const s16x8*)(Ab + r*64 + sl*8);
      }
      #pragma unroll
      for (int n = 0; n < 4; ++n) {
        int r = wn*64 + n*16 + lr;
        int sl = (ks*4 + lk) ^ (r & 7);
        bfv[n] = *(const s16x8*)(Bb + r*64 + sl*8);
      }
      #pragma unroll
      for (int m = 0; m < 4; ++m)
        #pragma unroll
        for (int n = 0; n < 4; ++n)
          acc[m][n] = __builtin_amdgcn_mfma_f32_16x16x32_bf16(af[m], bfv[n], acc[m][n], 0, 0, 0);
    }
    __syncthreads();
  }

  #pragma unroll
  for (int m = 0; m < 4; ++m) {
    #pragma unroll
    for (int n = 0; n < 4; ++n) {
      #pragma unroll
      for (int r2 = 0; r2 < 4; ++r2) {
        int row = m0 + wm*64 + m*16 + lk*4 + r2;   // C/D: row=(lane>>4)*4+reg
        int col = n0 + wn*64 + n*16 + lr;          //       col=lane&15
        float vv = acc[m][n][r2] + bias[col];
        if (act) vv = gelu_exact(vv);
        size_t off = (size_t)row * N + col;
        if (res)  vv = res[off] + rscale * vv;
        if (outf) outf[off] = vv;
        if (outb) outb[off] = f2b(vv);
        if (qd) {
          int part = col >> 9, h = (col >> 6) & 7, dh = col & 63;
          int b = row >> 10, t = row & (T_-1);
          float* dst = part == 0 ? qd : (part == 1 ? kd : vd);
          dst[(((size_t)(b*H_ + h))*T_ + t)*64 + dh] = vv;
        }
      }
    }
  }
}

// ---- WavLM relative-position buckets [T,T]
__global__ void k_bucket(int* __restrict__ bucket) {
  int idx = blockIdx.x*256 + threadIdx.x;
  int t = idx >> 10, s = idx & 1023;
  int rel = s - t;
  int sign = rel >= 0 ? 1 : 0;
  int a = rel >= 0 ? rel : -rel;
  int bkt;
  if (a < 80) bkt = a;
  else {
    float lr = logf((float)a / 80.f) / 2.30258509299404568402f;
    int lp = 80 + (int)(lr * 80.f);
    bkt = lp < 159 ? lp : 159;
  }
  bucket[idx] = bkt + sign*160;
}

// ---- attention: block = (b, h, 16-query tile); K/V staged in LDS, online softmax
__global__ __launch_bounds__(256) void k_attn2(
    const float* __restrict__ Qf, const float* __restrict__ Kf, const float* __restrict__ Vf,
    const int* __restrict__ bucket, const float* __restrict__ rel,
    const float* __restrict__ gu, const float* __restrict__ gw, const float* __restrict__ gs,
    u16* __restrict__ outb)
{
  __shared__ float qs[16][68];
  __shared__ float Kl[64][68];
  __shared__ float Vl[64][68];
  __shared__ float pl[16][64];
  __shared__ float coef[16];
  int blk = blockIdx.x;
  int tq = blk & 63;
  int h  = (blk >> 6) & 7;
  int b  = blk >> 9;
  int tid = threadIdx.x;
  int t0 = tq * 16;
  const float* qbase = Qf + (((size_t)(b*H_+h))*T_ + t0)*64;
  {
    int r = tid >> 4, c = (tid & 15) << 2;
    *(float4*)&qs[r][c] = *(const float4*)(qbase + (size_t)r*64 + c);
  }
  __syncthreads();
  if (tid < 16) {
    float vu = 0.f, vw = 0.f;
    const float* guh = gu + h*64; const float* gwh = gw + h*64;
    for (int kk = 0; kk < 64; ++kk){ float qv = qs[tid][kk]; vu += qv*guh[kk]; vw += qv*gwh[kk]; }
    float g1 = sigm(vu), g2 = sigm(vw);
    coef[tid] = 1.f + g1 + (1.f-g1)*gs[h]*g2;
  }
  __syncthreads();
  int qi = tid >> 4, sg = tid & 15;
  float mcur = -1e30f, lsum = 0.f;
  float o0=0.f, o1=0.f, o2=0.f, o3=0.f;
  const float* kb = Kf + ((size_t)(b*H_+h))*T_*64;
  const float* vb = Vf + ((size_t)(b*H_+h))*T_*64;
  const int* brow = bucket + (size_t)(t0+qi)*T_;
  float cf = coef[qi];
  int d = sg << 2;
  for (int st = 0; st < 16; ++st) {
    int s0 = st*64;
    __syncthreads();
    #pragma unroll
    for (int i = 0; i < 4; ++i) {
      int fl = i*256 + tid;
      int r = fl >> 4, c = (fl & 15) << 2;
      *(float4*)&Kl[r][c] = *(const float4*)(kb + (size_t)(s0+r)*64 + c);
      *(float4*)&Vl[r][c] = *(const float4*)(vb + (size_t)(s0+r)*64 + c);
    }
    __syncthreads();
    float sc[4];
    float tmax = -1e30f;
    #pragma unroll
    for (int si = 0; si < 4; ++si) {
      int sl = sg + 16*si;
      float a = 0.f;
      #pragma unroll
      for (int kk = 0; kk < 64; kk += 4) {
        float4 kv = *(const float4*)&Kl[sl][kk];
        a += qs[qi][kk]*kv.x + qs[qi][kk+1]*kv.y + qs[qi][kk+2]*kv.z + qs[qi][kk+3]*kv.w;
      }
      float bias = cf * rel[brow[s0+sl]*H_ + h];
      sc[si] = a*0.125f + bias;
      tmax = fmaxf(tmax, sc[si]);
    }
    #pragma unroll
    for (int off = 1; off < 16; off <<= 1)
      tmax = fmaxf(tmax, __shfl_xor(tmax, off));
    float mnew = fmaxf(mcur, tmax);
    float scale = expf(mcur - mnew);
    float psum = 0.f;
    #pragma unroll
    for (int si = 0; si < 4; ++si) {
      float e = expf(sc[si] - mnew);
      pl[qi][sg + 16*si] = e;
      psum += e;
    }
    #pragma unroll
    for (int off = 1; off < 16; off <<= 1)
      psum += __shfl_xor(psum, off);
    lsum = lsum*scale + psum;
    o0 *= scale; o1 *= scale; o2 *= scale; o3 *= scale;
    mcur = mnew;
    __syncthreads();
    #pragma unroll 8
    for (int ss = 0; ss < 64; ++ss) {
      float p = pl[qi][ss];
      float4 vv = *(const float4*)&Vl[ss][d];
      o0 += p*vv.x; o1 += p*vv.y; o2 += p*vv.z; o3 += p*vv.w;
    }
  }
  float inv = 1.f / lsum;
  size_t ob = ((size_t)(b*T_) + t0 + qi)*512 + h*64 + d;
  ushort4 pk;
  pk.x = f2b(o0*inv); pk.y = f2b(o1*inv); pk.z = f2b(o2*inv); pk.w = f2b(o3*inv);
  *(ushort4*)(outb + ob) = pk;
}

// ---- GroupNorm stats, two stage
__global__ __launch_bounds__(256) void k_gn_part(const float* __restrict__ x, float2* __restrict__ part) {
  int b = blockIdx.y, g = blockIdx.x;   // 64 slices per batch
  const float* xb = x + (size_t)b*(D_*T_) + (size_t)g*8192;
  float s = 0.f, s2 = 0.f;
  for (int i = threadIdx.x; i < 2048; i += 256) {
    float4 v4 = ((const float4*)xb)[i];
    s  += v4.x + v4.y + v4.z + v4.w;
    s2 += v4.x*v4.x + v4.y*v4.y + v4.z*v4.z + v4.w*v4.w;
  }
  __shared__ float rs[256], rq[256];
  rs[threadIdx.x] = s; rq[threadIdx.x] = s2; __syncthreads();
  for (int off = 128; off; off >>= 1) {
    if (threadIdx.x < off) { rs[threadIdx.x] += rs[threadIdx.x+off]; rq[threadIdx.x] += rq[threadIdx.x+off]; }
    __syncthreads();
  }
  if (threadIdx.x == 0) part[b*64 + g] = make_float2(rs[0], rq[0]);
}

__global__ void k_gn_final(const float2* __restrict__ part, float2* __restrict__ stats) {
  int b = blockIdx.x;
  float2 p = part[b*64 + threadIdx.x];
  float s = p.x, s2 = p.y;
  for (int off = 32; off; off >>= 1) { s += __shfl_down(s, off); s2 += __shfl_down(s2, off); }
  if (threadIdx.x == 0) {
    float n = (float)(D_*T_);
    float mean = s/n;
    float var = s2/n - mean*mean;
    stats[b] = make_float2(mean, rsqrtf(var + 1e-5f));
  }
}

__global__ void k_gn_apply(const float* __restrict__ x, const float2* __restrict__ stats,
                           const float* __restrict__ g, const float* __restrict__ bta,
                           u16* __restrict__ o, int silu_flag)
{
  size_t idx = (size_t)blockIdx.x*256 + threadIdx.x; // B*T*D
  int dd = idx & (D_-1);
  int b = (int)(idx >> 19);
  float2 st = stats[b];
  float v = (x[idx]-st.x)*st.y*g[dd] + bta[dd];
  if (silu_flag) v = v*sigm(v);
  o[idx] = f2b(v);
}

__global__ void k_glu(const float* __restrict__ h2, float* __restrict__ g) {
  size_t idx = (size_t)blockIdx.x*256 + threadIdx.x; // B*T*512
  int dd = idx & 511;
  size_t row = idx >> 9;
  float a = h2[row*1024 + dd], bb = h2[row*1024 + 512 + dd];
  g[idx] = a * sigm(bb);
}

__global__ void k_dwconv(const float* __restrict__ g, const float* __restrict__ w,
                         const float* __restrict__ bias, float* __restrict__ o)
{
  size_t idx = (size_t)blockIdx.x*256 + threadIdx.x; // B*T*D
  int dd = idx & 511;
  int t = (int)((idx >> 9) & (T_-1));
  int b = (int)(idx >> 19);
  float acc = bias[dd];
  const float* gb = g + (size_t)b*T_*D_;
  #pragma unroll
  for (int kk = 0; kk < 31; ++kk) {
    int tt = t + kk - 15;
    if (tt >= 0 && tt < T_) acc += gb[(size_t)tt*D_ + dd]*w[dd*31+kk];
  }
  o[idx] = acc;
}

extern "C" void kernel_launch(void* const* d_in, const int* in_sizes, int n_in,
                              void* d_out, int out_size, void* d_ws, size_t ws_size,
                              hipStream_t stream)
{
  const float* x      = (const float*)d_in[0];
  const float* ff1_w1 = (const float*)d_in[1];
  const float* ff1_b1 = (const float*)d_in[2];
  const float* ff1_w2 = (const float*)d_in[3];
  const float* ff1_b2 = (const float*)d_in[4];
  const float* qkv_w  = (const float*)d_in[5];
  const float* qkv_b  = (const float*)d_in[6];
  const float* out_w  = (const float*)d_in[7];
  const float* out_b  = (const float*)d_in[8];
  const float* gn1_g  = (const float*)d_in[9];
  const float* gn1_b  = (const float*)d_in[10];
  const float* pw1_w  = (const float*)d_in[11];
  const float* pw1_b  = (const float*)d_in[12];
  const float* dw_w   = (const float*)d_in[13];
  const float* dw_b   = (const float*)d_in[14];
  const float* gn2_g  = (const float*)d_in[15];
  const float* gn2_b  = (const float*)d_in[16];
  const float* pw2_w  = (const float*)d_in[17];
  const float* pw2_b  = (const float*)d_in[18];
  const float* ff2_w1 = (const float*)d_in[19];
  const float* ff2_b1 = (const float*)d_in[20];
  const float* ff2_w2 = (const float*)d_in[21];
  const float* ff2_b2 = (const float*)d_in[22];
  const float* rel_embed = (const float*)d_in[23];
  const float* gate_u = (const float*)d_in[24];
  const float* gate_w = (const float*)d_in[25];
  const float* gate_scale = (const float*)d_in[26];

  char* ws = (char*)d_ws;
  const size_t MB = (size_t)1 << 20;
  float* s0f  = (float*)(ws + 0*MB);    // 8MB, later S2f
  u16*   s0b  = (u16*)  (ws + 8*MB);    // 4MB, later attb
  u16*   h1b  = (u16*)  (ws + 12*MB);   // 16MB, later h3b
  float* Sf   = (float*)(ws + 28*MB);   // 8MB, later dcf, later Sout
  u16*   Sb   = (u16*)  (ws + 36*MB);   // 4MB, later gn1b/gn2b
  float* Qf   = (float*)(ws + 40*MB);   // 8MB, later h2f(16MB)/S3f/S3b
  float* Kf   = (float*)(ws + 48*MB);   // 8MB
  float* Vf   = (float*)(ws + 56*MB);   // 8MB, later gluf
  // aliases
  float* S2f  = (float*)(ws + 0*MB);
  u16*   attb = (u16*)  (ws + 8*MB);
  u16*   gn1b = (u16*)  (ws + 36*MB);
  float* h2f  = (float*)(ws + 40*MB);   // 16MB [M,1024]
  float* gluf = (float*)(ws + 56*MB);
  float* dcf  = (float*)(ws + 28*MB);
  u16*   gn2b = (u16*)  (ws + 36*MB);
  float* S3f  = (float*)(ws + 40*MB);
  u16*   S3b  = (u16*)  (ws + 48*MB);
  u16*   h3b  = (u16*)  (ws + 12*MB);
  float* Sout = (float*)(ws + 28*MB);
  // weights bf16 (2MB slots)
  u16* ff1w1t = (u16*)(ws + 64*MB);   // [2048][512]
  u16* ff1w2t = (u16*)(ws + 66*MB);   // [512][2048]
  u16* qkvt   = (u16*)(ws + 68*MB);   // [1536][512]
  u16* outt   = (u16*)(ws + 70*MB);   // [512][512]
  u16* pw1t   = (u16*)(ws + 72*MB);   // [1024][512]
  u16* pw2t   = (u16*)(ws + 74*MB);   // [512][512]
  u16* ff2w1t = (u16*)(ws + 76*MB);   // [2048][512]
  u16* ff2w2t = (u16*)(ws + 78*MB);   // [512][2048]
  int* BKT    = (int*)(ws + 80*MB);   // 4MB
  float2* part1 = (float2*)(ws + 84*MB);
  float2* part2 = (float2*)(ws + 84*MB + 8192);
  float2* st1   = (float2*)(ws + 84*MB + 16384);
  float2* st2   = (float2*)(ws + 84*MB + 16384 + 64);

  const int M = B_*T_;
  dim3 blk(256);

  // weight prep
  k_wt<<<dim3(FFD/32, D_/32), blk, 0, stream>>>(ff1_w1, ff1w1t, D_, FFD);
  k_wt<<<dim3(D_/32, FFD/32), blk, 0, stream>>>(ff1_w2, ff1w2t, FFD, D_);
  k_wt<<<dim3(1536/32, D_/32), blk, 0, stream>>>(qkv_w, qkvt, D_, 1536);
  k_wt<<<dim3(D_/32, D_/32), blk, 0, stream>>>(out_w, outt, D_, D_);
  k_wt<<<dim3(1024/32, D_/32), blk, 0, stream>>>(pw1_w, pw1t, D_, 1024);
  k_wt<<<dim3(D_/32, D_/32), blk, 0, stream>>>(pw2_w, pw2t, D_, D_);
  k_wt<<<dim3(FFD/32, D_/32), blk, 0, stream>>>(ff2_w1, ff2w1t, D_, FFD);
  k_wt<<<dim3(D_/32, FFD/32), blk, 0, stream>>>(ff2_w2, ff2w2t, FFD, D_);
  k_bucket<<<dim3((T_*T_)/256), blk, 0, stream>>>(BKT);

  k_xin<<<dim3(T_/32, D_/32, B_), blk, 0, stream>>>(x, s0f, s0b);

  // FFN1: h1 = gelu(s0 @ W1); S = s0 + 0.5*(h1 @ W2)
  k_gemm_mfma<<<dim3(FFD/128, M/128), blk, 0, stream>>>(s0b, ff1w1t, ff1_b1, nullptr, 0.f,
      nullptr, h1b, nullptr, nullptr, nullptr, M, FFD, D_, 1);
  k_gemm_mfma<<<dim3(D_/128, M/128), blk, 0, stream>>>(h1b, ff1w2t, ff1_b2, s0f, 0.5f,
      Sf, Sb, nullptr, nullptr, nullptr, M, D_, FFD, 0);
  // QKV (scatter epilogue)
  k_gemm_mfma<<<dim3(1536/128, M/128), blk, 0, stream>>>(Sb, qkvt, qkv_b, nullptr, 0.f,
      nullptr, nullptr, Qf, Kf, Vf, M, 1536, D_, 0);
  // attention
  k_attn2<<<dim3(B_*H_*64), blk, 0, stream>>>(Qf, Kf, Vf, BKT, rel_embed, gate_u, gate_w, gate_scale, attb);
  // out proj + residual
  k_gemm_mfma<<<dim3(D_/128, M/128), blk, 0, stream>>>(attb, outt, out_b, Sf, 1.f,
      S2f, nullptr, nullptr, nullptr, nullptr, M, D_, D_, 0);
  // conv module
  k_gn_part<<<dim3(64, B_), blk, 0, stream>>>(S2f, part1);
  k_gn_final<<<dim3(B_), dim3(64), 0, stream>>>(part1, st1);
  k_gn_apply<<<dim3((M*D_)/256), blk, 0, stream>>>(S2f, st1, gn1_g, gn1_b, gn1b, 0);
  k_gemm_mfma<<<dim3(1024/128, M/128), blk, 0, stream>>>(gn1b, pw1t, pw1_b, nullptr, 0.f,
      h2f, nullptr, nullptr, nullptr, nullptr, M, 1024, D_, 0);
  k_glu<<<dim3((M*512)/256), blk, 0, stream>>>(h2f, gluf);
  k_dwconv<<<dim3((M*D_)/256), blk, 0, stream>>>(gluf, dw_w, dw_b, dcf);
  k_gn_part<<<dim3(64, B_), blk, 0, stream>>>(dcf, part2);
  k_gn_final<<<dim3(B_), dim3(64), 0, stream>>>(part2, st2);
  k_gn_apply<<<dim3((M*D_)/256), blk, 0, stream>>>(dcf, st2, gn2_g, gn2_b, gn2b, 1);
  k_gemm_mfma<<<dim3(D_/128, M/128), blk, 0, stream>>>(gn2b, pw2t, pw2_b, S2f, 1.f,
      S3f, S3b, nullptr, nullptr, nullptr, M, D_, D_, 0);
  // FFN2
  k_gemm_mfma<<<dim3(FFD/128, M/128), blk, 0, stream>>>(S3b, ff2w1t, ff2_b1, nullptr, 0.f,
      nullptr, h3b, nullptr, nullptr, nullptr, M, FFD, D_, 1);
  k_gemm_mfma<<<dim3(D_/128, M/128), blk, 0, stream>>>(h3b, ff2w2t, ff2_b2, S3f, 0.5f,
      Sout, nullptr, nullptr, nullptr, nullptr, M, D_, FFD, 0);
  k_transpose_out<<<dim3(D_/32, T_/32, B_), blk, 0, stream>>>(Sout, (float*)d_out);
}

// Round 7
// 575.925 us; speedup vs baseline: 7.2696x; 1.5073x over previous
//
#include <hip/hip_runtime.h>
#include <hip/hip_bf16.h>
#include <math.h>

#define B_ 4
#define D_ 512
#define T_ 1024
#define H_ 8
#define FFD 2048

typedef unsigned short u16;
typedef short s16x8 __attribute__((ext_vector_type(8)));
typedef float f32x4 __attribute__((ext_vector_type(4)));

__device__ inline float sigm(float x){ return 1.f/(1.f+expf(-x)); }
__device__ inline float gelu_exact(float x){ return 0.5f*x*(1.f+erff(x*0.70710678118654752440f)); }
__device__ inline u16 f2b(float f){
  __hip_bfloat16 h = __float2bfloat16(f);
  return *reinterpret_cast<u16*>(&h);
}
__device__ inline float b2f(u16 u){ return __uint_as_float(((unsigned)u)<<16); }

__device__ inline void gl_lds16(const void* g, void* l) {
  __builtin_amdgcn_global_load_lds(
      (const __attribute__((address_space(1))) void*)g,
      (__attribute__((address_space(3))) void*)l, 16, 0, 0);
}

// ---- weight transpose+cast: W f32 [K][N] -> Wt bf16 [N][K]
__global__ __launch_bounds__(256) void k_wt(const float* __restrict__ w, u16* __restrict__ wt, int K, int N) {
  __shared__ float tile[32][33];
  int n0 = blockIdx.x*32, k0 = blockIdx.y*32;
  int c = threadIdx.x & 31, r = threadIdx.x >> 5;
  for (int rr = r; rr < 32; rr += 8)
    tile[rr][c] = w[(size_t)(k0+rr)*N + n0 + c];
  __syncthreads();
  for (int rr = r; rr < 32; rr += 8)
    wt[(size_t)(n0+rr)*K + k0 + c] = f2b(tile[c][rr]);
}

// ---- x f32 [B,D,T] -> s0 f32 [B,T,D] + bf16 copy
__global__ __launch_bounds__(256) void k_xin(const float* __restrict__ x, float* __restrict__ sf, u16* __restrict__ sb) {
  __shared__ float tile[32][33];
  int b = blockIdx.z;
  int d0 = blockIdx.y * 32;
  int t0 = blockIdx.x * 32;
  int c = threadIdx.x & 31, r = threadIdx.x >> 5;
  for (int rr = r; rr < 32; rr += 8)
    tile[rr][c] = x[((size_t)(b*D_ + d0 + rr))*T_ + t0 + c];
  __syncthreads();
  for (int rr = r; rr < 32; rr += 8) {
    float v = tile[c][rr];
    size_t o = ((size_t)(b*T_ + t0 + rr))*D_ + d0 + c;
    sf[o] = v; sb[o] = f2b(v);
  }
}

// ---- final: s f32 [B,T,D] -> out f32 [B,D,T]
__global__ __launch_bounds__(256) void k_transpose_out(const float* __restrict__ s, float* __restrict__ o) {
  __shared__ float tile[32][33];
  int b = blockIdx.z;
  int t0 = blockIdx.y * 32;
  int d0 = blockIdx.x * 32;
  int c = threadIdx.x & 31, r = threadIdx.x >> 5;
  for (int rr = r; rr < 32; rr += 8)
    tile[rr][c] = s[((size_t)(b*T_ + t0 + rr))*D_ + d0 + c];
  __syncthreads();
  for (int rr = r; rr < 32; rr += 8)
    o[((size_t)(b*D_ + d0 + rr))*T_ + t0 + c] = tile[c][rr];
}

// ---- MFMA GEMM: C[M,N] = epi(A[M,K]bf16 @ Wt[N,K]bf16^T + bias)
__global__ __launch_bounds__(256) void k_gemm_mfma(
    const u16* __restrict__ A, const u16* __restrict__ Wt,
    const float* __restrict__ bias, const float* __restrict__ res, float rscale,
    float* __restrict__ outf, u16* __restrict__ outb,
    u16* __restrict__ qd, u16* __restrict__ kd, u16* __restrict__ vd,
    int M, int N, int K, int act)
{
  __shared__ u16 Ab[128*64];
  __shared__ u16 Bb[128*64];
  int tid = threadIdx.x;
  int w = tid >> 6, lane = tid & 63;
  int lr = lane & 15, lk = lane >> 4;
  int wm = w >> 1, wn = w & 1;
  int m0 = blockIdx.y * 128, n0 = blockIdx.x * 128;
  f32x4 acc[4][4] = {};

  for (int kt = 0; kt < K; kt += 64) {
    #pragma unroll
    for (int i = 0; i < 4; ++i) {
      int slot = (w*4 + i)*64 + lane;
      int r = slot >> 3, sc = slot & 7;
      int cc = sc ^ (r & 7);
      gl_lds16(A  + (size_t)(m0 + r)*K + kt + cc*8, (char*)Ab + (size_t)(w*4+i)*1024);
      gl_lds16(Wt + (size_t)(n0 + r)*K + kt + cc*8, (char*)Bb + (size_t)(w*4+i)*1024);
    }
    __syncthreads();
    #pragma unroll
    for (int ks = 0; ks < 2; ++ks) {
      s16x8 af[4], bfv[4];
      #pragma unroll
      for (int m = 0; m < 4; ++m) {
        int r = wm*64 + m*16 + lr;
        int sl = (ks*4 + lk) ^ (r & 7);
        af[m] = *(const s16x8*)(Ab + r*64 + sl*8);
      }
      #pragma unroll
      for (int n = 0; n < 4; ++n) {
        int r = wn*64 + n*16 + lr;
        int sl = (ks*4 + lk) ^ (r & 7);
        bfv[n] = *(const s16x8*)(Bb + r*64 + sl*8);
      }
      #pragma unroll
      for (int m = 0; m < 4; ++m)
        #pragma unroll
        for (int n = 0; n < 4; ++n)
          acc[m][n] = __builtin_amdgcn_mfma_f32_16x16x32_bf16(af[m], bfv[n], acc[m][n], 0, 0, 0);
    }
    __syncthreads();
  }

  #pragma unroll
  for (int m = 0; m < 4; ++m) {
    #pragma unroll
    for (int n = 0; n < 4; ++n) {
      #pragma unroll
      for (int r2 = 0; r2 < 4; ++r2) {
        int row = m0 + wm*64 + m*16 + lk*4 + r2;
        int col = n0 + wn*64 + n*16 + lr;
        float vv = acc[m][n][r2] + bias[col];
        if (act) vv = gelu_exact(vv);
        size_t off = (size_t)row * N + col;
        if (res)  vv = res[off] + rscale * vv;
        if (outf) outf[off] = vv;
        if (outb) outb[off] = f2b(vv);
        if (qd) {
          int part = col >> 9, h = (col >> 6) & 7, dh = col & 63;
          int b = row >> 10, t = row & (T_-1);
          u16* dst = part == 0 ? qd : (part == 1 ? kd : vd);
          dst[(((size_t)(b*H_ + h))*T_ + t)*64 + dh] = f2b(vv);
        }
      }
    }
  }
}

// ---- per-head Toeplitz bias table: rbg[h][j] = rel_embed[bucket(j-1023)][h]
__global__ void k_rb(const float* __restrict__ rel_embed, float* __restrict__ rbg) {
  int idx = blockIdx.x*256 + threadIdx.x;    // 8*2048
  int h = idx >> 11, j = idx & 2047;
  if (j >= 2047) { rbg[idx] = 0.f; return; }
  int rel = j - 1023;
  int sign = rel >= 0 ? 1 : 0;
  int a = rel >= 0 ? rel : -rel;
  int bkt;
  if (a < 80) bkt = a;
  else {
    float lr = logf((float)a / 80.f) / 2.30258509299404568402f;
    int lp = 80 + (int)(lr * 80.f);
    bkt = lp < 159 ? lp : 159;
  }
  bkt += sign*160;
  rbg[idx] = rel_embed[bkt*H_ + h];
}

// ---- V transpose: vb bf16 [B,H,T,64] -> vtb bf16 [B,H,64,T]
__global__ __launch_bounds__(256) void k_vt(const u16* __restrict__ vb, u16* __restrict__ vtb) {
  __shared__ u16 tl[64][65];
  int blk = blockIdx.x;
  int tt0 = (blk & 15) * 64;
  size_t bh = (size_t)(blk >> 4);
  int tid = threadIdx.x;
  #pragma unroll
  for (int i = 0; i < 4; ++i) {
    int idx = i*256 + tid;
    int t = idx >> 4, d0 = (idx & 15) * 4;
    *(ushort4*)&tl[t][d0] = *(const ushort4*)(vb + (bh*T_ + tt0 + t)*64 + d0);
  }
  __syncthreads();
  #pragma unroll
  for (int i = 0; i < 4; ++i) {
    int idx = i*256 + tid;
    int dh = idx >> 4, t4 = (idx & 15) * 4;
    ushort4 o;
    o.x = tl[t4+0][dh]; o.y = tl[t4+1][dh]; o.z = tl[t4+2][dh]; o.w = tl[t4+3][dh];
    *(ushort4*)(vtb + (bh*64 + dh)*T_ + tt0 + t4) = o;
  }
}

// ---- MFMA flash attention: block=(b,h,64-q tile), 4 waves; K/Vt LDS tiles, online softmax
__global__ __launch_bounds__(256) void k_attn3(
    const u16* __restrict__ qb, const u16* __restrict__ kb, const u16* __restrict__ vtb,
    const float* __restrict__ rbg,
    const float* __restrict__ gu, const float* __restrict__ gw, const float* __restrict__ gs,
    u16* __restrict__ outb)
{
  __shared__ u16 Kl[64*64];
  __shared__ u16 Vtl[64*64];
  __shared__ u16 Pl[64*64];
  __shared__ float rb[2048];
  __shared__ float cf[64];
  int blk = blockIdx.x;
  int qt = blk & 15;
  int h  = (blk >> 4) & 7;
  int b  = blk >> 7;
  int tid = threadIdx.x;
  int w = tid >> 6, lane = tid & 63;
  int lr = lane & 15, lk = lane >> 4;
  int g = lane >> 4;
  int t0 = qt * 64;
  size_t bh = (size_t)(b*H_ + h);

  for (int j = tid; j < 2048; j += 256) rb[j] = rbg[h*2048 + j];
  if (tid < 64) {
    const u16* qrow = qb + (bh*T_ + t0 + tid)*64;
    float vu = 0.f, vw = 0.f;
    for (int kk2 = 0; kk2 < 64; ++kk2) {
      float qv = b2f(qrow[kk2]);
      vu += qv * gu[h*64+kk2];
      vw += qv * gw[h*64+kk2];
    }
    float g1 = sigm(vu), g2 = sigm(vw);
    cf[tid] = 1.f + g1 + (1.f-g1)*gs[h]*g2;
  }
  const u16* qbase = qb + (bh*T_ + t0 + w*16 + lr)*64;
  s16x8 qa0 = *(const s16x8*)(qbase + lk*8);
  s16x8 qa1 = *(const s16x8*)(qbase + 32 + lk*8);

  f32x4 O[4] = {};
  float mcur[4] = {-1e30f,-1e30f,-1e30f,-1e30f};
  float lsum[4] = {0.f,0.f,0.f,0.f};
  const f32x4 zero = {0.f,0.f,0.f,0.f};
  __syncthreads();

  for (int kt = 0; kt < 16; ++kt) {
    #pragma unroll
    for (int i = 0; i < 2; ++i) {
      int slot = (i*4 + w)*64 + lane;
      int r = slot >> 3, scc = slot & 7;
      int cc = scc ^ (r & 7);
      gl_lds16(kb  + (bh*T_ + kt*64 + r)*64 + cc*8, (char*)Kl  + (i*4+w)*1024);
      gl_lds16(vtb + (bh*64 + r)*T_ + kt*64 + cc*8, (char*)Vtl + (i*4+w)*1024);
    }
    __syncthreads();
    // QK^T
    f32x4 sc[4];
    #pragma unroll
    for (int n = 0; n < 4; ++n) {
      int row = n*16 + lr;
      int c0 = (0*4 + lk) ^ (row & 7);
      int c1 = (1*4 + lk) ^ (row & 7);
      s16x8 kb0 = *(const s16x8*)(Kl + row*64 + c0*8);
      s16x8 kb1 = *(const s16x8*)(Kl + row*64 + c1*8);
      f32x4 t = __builtin_amdgcn_mfma_f32_16x16x32_bf16(qa0, kb0, zero, 0, 0, 0);
      sc[n]   = __builtin_amdgcn_mfma_f32_16x16x32_bf16(qa1, kb1, t, 0, 0, 0);
    }
    // bias + per-row max (row = w*16 + g*4 + r2, col = n*16 + lr)
    float tmax[4];
    #pragma unroll
    for (int r2 = 0; r2 < 4; ++r2) {
      int q_local = w*16 + g*4 + r2;
      float cfv = cf[q_local];
      int qabs = t0 + q_local;
      float mx = -1e30f;
      #pragma unroll
      for (int n = 0; n < 4; ++n) {
        int sabs = kt*64 + n*16 + lr;
        float v = sc[n][r2]*0.125f + cfv * rb[sabs - qabs + 1023];
        sc[n][r2] = v;
        mx = fmaxf(mx, v);
      }
      tmax[r2] = mx;
    }
    #pragma unroll
    for (int mk = 1; mk < 16; mk <<= 1)
      #pragma unroll
      for (int r2 = 0; r2 < 4; ++r2)
        tmax[r2] = fmaxf(tmax[r2], __shfl_xor(tmax[r2], mk));
    // online softmax update; write P (bf16, swizzled)
    float scl[4], psum[4];
    #pragma unroll
    for (int r2 = 0; r2 < 4; ++r2) {
      float mnew = fmaxf(mcur[r2], tmax[r2]);
      scl[r2] = __expf(mcur[r2] - mnew);
      mcur[r2] = mnew;
      int q_local = w*16 + g*4 + r2;
      float ps = 0.f;
      #pragma unroll
      for (int n = 0; n < 4; ++n) {
        float e = __expf(sc[n][r2] - mnew);
        ps += e;
        int s_local = n*16 + lr;
        Pl[q_local*64 + (((s_local>>3) ^ (q_local&7))<<3) + (s_local&7)] = f2b(e);
      }
      psum[r2] = ps;
    }
    #pragma unroll
    for (int mk = 1; mk < 16; mk <<= 1)
      #pragma unroll
      for (int r2 = 0; r2 < 4; ++r2)
        psum[r2] += __shfl_xor(psum[r2], mk);
    #pragma unroll
    for (int r2 = 0; r2 < 4; ++r2) lsum[r2] = lsum[r2]*scl[r2] + psum[r2];
    #pragma unroll
    for (int n = 0; n < 4; ++n)
      #pragma unroll
      for (int r2 = 0; r2 < 4; ++r2)
        O[n][r2] *= scl[r2];
    __syncthreads();
    // PV: O[q][dh] += P[q][s] * Vt[dh][s]
    int qrow = w*16 + lr;
    int pc0 = (0*4 + lk) ^ (qrow & 7), pc1 = (1*4 + lk) ^ (qrow & 7);
    s16x8 pa0 = *(const s16x8*)(Pl + qrow*64 + pc0*8);
    s16x8 pa1 = *(const s16x8*)(Pl + qrow*64 + pc1*8);
    #pragma unroll
    for (int n = 0; n < 4; ++n) {
      int dh = n*16 + lr;
      int c0 = (0*4 + lk) ^ (dh & 7), c1 = (1*4 + lk) ^ (dh & 7);
      s16x8 vb0 = *(const s16x8*)(Vtl + dh*64 + c0*8);
      s16x8 vb1 = *(const s16x8*)(Vtl + dh*64 + c1*8);
      O[n] = __builtin_amdgcn_mfma_f32_16x16x32_bf16(pa0, vb0, O[n], 0, 0, 0);
      O[n] = __builtin_amdgcn_mfma_f32_16x16x32_bf16(pa1, vb1, O[n], 0, 0, 0);
    }
    __syncthreads();
  }
  float inv[4];
  #pragma unroll
  for (int r2 = 0; r2 < 4; ++r2) inv[r2] = 1.f / lsum[r2];
  #pragma unroll
  for (int n = 0; n < 4; ++n)
    #pragma unroll
    for (int r2 = 0; r2 < 4; ++r2) {
      int q = t0 + w*16 + g*4 + r2;
      int dh = n*16 + lr;
      outb[((size_t)(b*T_) + q)*512 + h*64 + dh] = f2b(O[n][r2]*inv[r2]);
    }
}

// ---- GroupNorm stats, two stage
__global__ __launch_bounds__(256) void k_gn_part(const float* __restrict__ x, float2* __restrict__ part) {
  int b = blockIdx.y, g = blockIdx.x;
  const float* xb = x + (size_t)b*(D_*T_) + (size_t)g*8192;
  float s = 0.f, s2 = 0.f;
  for (int i = threadIdx.x; i < 2048; i += 256) {
    float4 v4 = ((const float4*)xb)[i];
    s  += v4.x + v4.y + v4.z + v4.w;
    s2 += v4.x*v4.x + v4.y*v4.y + v4.z*v4.z + v4.w*v4.w;
  }
  __shared__ float rs[256], rq[256];
  rs[threadIdx.x] = s; rq[threadIdx.x] = s2; __syncthreads();
  for (int off = 128; off; off >>= 1) {
    if (threadIdx.x < off) { rs[threadIdx.x] += rs[threadIdx.x+off]; rq[threadIdx.x] += rq[threadIdx.x+off]; }
    __syncthreads();
  }
  if (threadIdx.x == 0) part[b*64 + g] = make_float2(rs[0], rq[0]);
}

__global__ void k_gn_final(const float2* __restrict__ part, float2* __restrict__ stats) {
  int b = blockIdx.x;
  float2 p = part[b*64 + threadIdx.x];
  float s = p.x, s2 = p.y;
  for (int off = 32; off; off >>= 1) { s += __shfl_down(s, off); s2 += __shfl_down(s2, off); }
  if (threadIdx.x == 0) {
    float n = (float)(D_*T_);
    float mean = s/n;
    float var = s2/n - mean*mean;
    stats[b] = make_float2(mean, rsqrtf(var + 1e-5f));
  }
}

__global__ void k_gn_apply(const float* __restrict__ x, const float2* __restrict__ stats,
                           const float* __restrict__ g, const float* __restrict__ bta,
                           u16* __restrict__ o, int silu_flag)
{
  size_t idx = (size_t)blockIdx.x*256 + threadIdx.x;
  int dd = idx & (D_-1);
  int b = (int)(idx >> 19);
  float2 st = stats[b];
  float v = (x[idx]-st.x)*st.y*g[dd] + bta[dd];
  if (silu_flag) v = v*sigm(v);
  o[idx] = f2b(v);
}

__global__ void k_glu(const float* __restrict__ h2, float* __restrict__ g) {
  size_t idx = (size_t)blockIdx.x*256 + threadIdx.x;
  int dd = idx & 511;
  size_t row = idx >> 9;
  float a = h2[row*1024 + dd], bb = h2[row*1024 + 512 + dd];
  g[idx] = a * sigm(bb);
}

__global__ void k_dwconv(const float* __restrict__ g, const float* __restrict__ w,
                         const float* __restrict__ bias, float* __restrict__ o)
{
  size_t idx = (size_t)blockIdx.x*256 + threadIdx.x;
  int dd = idx & 511;
  int t = (int)((idx >> 9) & (T_-1));
  int b = (int)(idx >> 19);
  float acc = bias[dd];
  const float* gb = g + (size_t)b*T_*D_;
  #pragma unroll
  for (int kk = 0; kk < 31; ++kk) {
    int tt = t + kk - 15;
    if (tt >= 0 && tt < T_) acc += gb[(size_t)tt*D_ + dd]*w[dd*31+kk];
  }
  o[idx] = acc;
}

extern "C" void kernel_launch(void* const* d_in, const int* in_sizes, int n_in,
                              void* d_out, int out_size, void* d_ws, size_t ws_size,
                              hipStream_t stream)
{
  const float* x      = (const float*)d_in[0];
  const float* ff1_w1 = (const float*)d_in[1];
  const float* ff1_b1 = (const float*)d_in[2];
  const float* ff1_w2 = (const float*)d_in[3];
  const float* ff1_b2 = (const float*)d_in[4];
  const float* qkv_w  = (const float*)d_in[5];
  const float* qkv_b  = (const float*)d_in[6];
  const float* out_w  = (const float*)d_in[7];
  const float* out_b  = (const float*)d_in[8];
  const float* gn1_g  = (const float*)d_in[9];
  const float* gn1_b  = (const float*)d_in[10];
  const float* pw1_w  = (const float*)d_in[11];
  const float* pw1_b  = (const float*)d_in[12];
  const float* dw_w   = (const float*)d_in[13];
  const float* dw_b   = (const float*)d_in[14];
  const float* gn2_g  = (const float*)d_in[15];
  const float* gn2_b  = (const float*)d_in[16];
  const float* pw2_w  = (const float*)d_in[17];
  const float* pw2_b  = (const float*)d_in[18];
  const float* ff2_w1 = (const float*)d_in[19];
  const float* ff2_b1 = (const float*)d_in[20];
  const float* ff2_w2 = (const float*)d_in[21];
  const float* ff2_b2 = (const float*)d_in[22];
  const float* rel_embed = (const float*)d_in[23];
  const float* gate_u = (const float*)d_in[24];
  const float* gate_w = (const float*)d_in[25];
  const float* gate_scale = (const float*)d_in[26];

  char* ws = (char*)d_ws;
  const size_t MB = (size_t)1 << 20;
  float* s0f  = (float*)(ws + 0*MB);
  u16*   s0b  = (u16*)  (ws + 8*MB);
  u16*   h1b  = (u16*)  (ws + 12*MB);
  float* Sf   = (float*)(ws + 28*MB);
  u16*   Sb   = (u16*)  (ws + 36*MB);
  u16*   qbb  = (u16*)  (ws + 40*MB);   // [B,H,T,64] bf16
  u16*   kbb  = (u16*)  (ws + 44*MB);
  u16*   vbb  = (u16*)  (ws + 48*MB);
  u16*   vtb  = (u16*)  (ws + 52*MB);   // [B,H,64,T] bf16
  // aliases
  float* S2f  = (float*)(ws + 0*MB);
  u16*   attb = (u16*)  (ws + 8*MB);
  u16*   gn1b = (u16*)  (ws + 36*MB);
  float* h2f  = (float*)(ws + 40*MB);   // 16MB (over q/k/v/vt, dead after attn)
  float* gluf = (float*)(ws + 56*MB);
  float* dcf  = (float*)(ws + 28*MB);
  u16*   gn2b = (u16*)  (ws + 36*MB);
  float* S3f  = (float*)(ws + 40*MB);
  u16*   S3b  = (u16*)  (ws + 48*MB);
  u16*   h3b  = (u16*)  (ws + 12*MB);
  float* Sout = (float*)(ws + 28*MB);
  // weights bf16
  u16* ff1w1t = (u16*)(ws + 64*MB);
  u16* ff1w2t = (u16*)(ws + 66*MB);
  u16* qkvt   = (u16*)(ws + 68*MB);
  u16* outt   = (u16*)(ws + 70*MB);
  u16* pw1t   = (u16*)(ws + 72*MB);
  u16* pw2t   = (u16*)(ws + 74*MB);
  u16* ff2w1t = (u16*)(ws + 76*MB);
  u16* ff2w2t = (u16*)(ws + 78*MB);
  float* rbg  = (float*)(ws + 80*MB);   // [8][2048] f32
  float2* part1 = (float2*)(ws + 84*MB);
  float2* part2 = (float2*)(ws + 84*MB + 8192);
  float2* st1   = (float2*)(ws + 84*MB + 16384);
  float2* st2   = (float2*)(ws + 84*MB + 16384 + 64);

  const int M = B_*T_;
  dim3 blk(256);

  k_wt<<<dim3(FFD/32, D_/32), blk, 0, stream>>>(ff1_w1, ff1w1t, D_, FFD);
  k_wt<<<dim3(D_/32, FFD/32), blk, 0, stream>>>(ff1_w2, ff1w2t, FFD, D_);
  k_wt<<<dim3(1536/32, D_/32), blk, 0, stream>>>(qkv_w, qkvt, D_, 1536);
  k_wt<<<dim3(D_/32, D_/32), blk, 0, stream>>>(out_w, outt, D_, D_);
  k_wt<<<dim3(1024/32, D_/32), blk, 0, stream>>>(pw1_w, pw1t, D_, 1024);
  k_wt<<<dim3(D_/32, D_/32), blk, 0, stream>>>(pw2_w, pw2t, D_, D_);
  k_wt<<<dim3(FFD/32, D_/32), blk, 0, stream>>>(ff2_w1, ff2w1t, D_, FFD);
  k_wt<<<dim3(D_/32, FFD/32), blk, 0, stream>>>(ff2_w2, ff2w2t, FFD, D_);
  k_rb<<<dim3(64), blk, 0, stream>>>(rel_embed, rbg);

  k_xin<<<dim3(T_/32, D_/32, B_), blk, 0, stream>>>(x, s0f, s0b);

  // FFN1
  k_gemm_mfma<<<dim3(FFD/128, M/128), blk, 0, stream>>>(s0b, ff1w1t, ff1_b1, nullptr, 0.f,
      nullptr, h1b, nullptr, nullptr, nullptr, M, FFD, D_, 1);
  k_gemm_mfma<<<dim3(D_/128, M/128), blk, 0, stream>>>(h1b, ff1w2t, ff1_b2, s0f, 0.5f,
      Sf, Sb, nullptr, nullptr, nullptr, M, D_, FFD, 0);
  // QKV (bf16 scatter)
  k_gemm_mfma<<<dim3(1536/128, M/128), blk, 0, stream>>>(Sb, qkvt, qkv_b, nullptr, 0.f,
      nullptr, nullptr, qbb, kbb, vbb, M, 1536, D_, 0);
  k_vt<<<dim3(B_*H_*16), blk, 0, stream>>>(vbb, vtb);
  // attention
  k_attn3<<<dim3(B_*H_*16), blk, 0, stream>>>(qbb, kbb, vtb, rbg, gate_u, gate_w, gate_scale, attb);
  // out proj + residual
  k_gemm_mfma<<<dim3(D_/128, M/128), blk, 0, stream>>>(attb, outt, out_b, Sf, 1.f,
      S2f, nullptr, nullptr, nullptr, nullptr, M, D_, D_, 0);
  // conv module
  k_gn_part<<<dim3(64, B_), blk, 0, stream>>>(S2f, part1);
  k_gn_final<<<dim3(B_), dim3(64), 0, stream>>>(part1, st1);
  k_gn_apply<<<dim3((M*D_)/256), blk, 0, stream>>>(S2f, st1, gn1_g, gn1_b, gn1b, 0);
  k_gemm_mfma<<<dim3(1024/128, M/128), blk, 0, stream>>>(gn1b, pw1t, pw1_b, nullptr, 0.f,
      h2f, nullptr, nullptr, nullptr, nullptr, M, 1024, D_, 0);
  k_glu<<<dim3((M*512)/256), blk, 0, stream>>>(h2f, gluf);
  k_dwconv<<<dim3((M*D_)/256), blk, 0, stream>>>(gluf, dw_w, dw_b, dcf);
  k_gn_part<<<dim3(64, B_), blk, 0, stream>>>(dcf, part2);
  k_gn_final<<<dim3(B_), dim3(64), 0, stream>>>(part2, st2);
  k_gn_apply<<<dim3((M*D_)/256), blk, 0, stream>>>(dcf, st2, gn2_g, gn2_b, gn2b, 1);
  k_gemm_mfma<<<dim3(D_/128, M/128), blk, 0, stream>>>(gn2b, pw2t, pw2_b, S2f, 1.f,
      S3f, S3b, nullptr, nullptr, nullptr, M, D_, D_, 0);
  // FFN2
  k_gemm_mfma<<<dim3(FFD/128, M/128), blk, 0, stream>>>(S3b, ff2w1t, ff2_b1, nullptr, 0.f,
      nullptr, h3b, nullptr, nullptr, nullptr, M, FFD, D_, 1);
  k_gemm_mfma<<<dim3(D_/128, M/128), blk, 0, stream>>>(h3b, ff2w2t, ff2_b2, S3f, 0.5f,
      Sout, nullptr, nullptr, nullptr, nullptr, M, D_, FFD, 0);
  k_transpose_out<<<dim3(D_/32, T_/32, B_), blk, 0, stream>>>(Sout, (float*)d_out);
}

// Round 9
// 550.144 us; speedup vs baseline: 7.6103x; 1.0469x over previous
//
#include <hip/hip_runtime.h>
#include <hip/hip_bf16.h>
#include <math.h>

#define B_ 4
#define D_ 512
#define T_ 1024
#define H_ 8
#define FFD 2048

typedef unsigned short u16;
typedef short s16x8 __attribute__((ext_vector_type(8)));
typedef float f32x4 __attribute__((ext_vector_type(4)));

__device__ inline float sigm(float x){ return 1.f/(1.f+expf(-x)); }
__device__ inline float gelu_exact(float x){ return 0.5f*x*(1.f+erff(x*0.70710678118654752440f)); }
__device__ inline u16 f2b(float f){
  __hip_bfloat16 h = __float2bfloat16(f);
  return *reinterpret_cast<u16*>(&h);
}
__device__ inline float b2f(u16 u){ return __uint_as_float(((unsigned)u)<<16); }

__device__ inline void gl_lds16(const void* g, void* l) {
  __builtin_amdgcn_global_load_lds(
      (const __attribute__((address_space(1))) void*)g,
      (__attribute__((address_space(3))) void*)l, 16, 0, 0);
}

// ---- weight transpose+cast: W f32 [K][N] -> Wt bf16 [N][K]
__global__ __launch_bounds__(256) void k_wt(const float* __restrict__ w, u16* __restrict__ wt, int K, int N) {
  __shared__ float tile[32][33];
  int n0 = blockIdx.x*32, k0 = blockIdx.y*32;
  int c = threadIdx.x & 31, r = threadIdx.x >> 5;
  for (int rr = r; rr < 32; rr += 8)
    tile[rr][c] = w[(size_t)(k0+rr)*N + n0 + c];
  __syncthreads();
  for (int rr = r; rr < 32; rr += 8)
    wt[(size_t)(n0+rr)*K + k0 + c] = f2b(tile[c][rr]);
}

// ---- pw1 weight: transpose+cast with GLU column interleave.
// logical col L in [0,1024): interleaved row np = L<512 ? 2L : 2(L-512)+1
__global__ __launch_bounds__(256) void k_wt_glu(const float* __restrict__ w, u16* __restrict__ wt, int K, int N) {
  __shared__ float tile[32][33];
  int n0 = blockIdx.x*32, k0 = blockIdx.y*32;
  int c = threadIdx.x & 31, r = threadIdx.x >> 5;
  for (int rr = r; rr < 32; rr += 8)
    tile[rr][c] = w[(size_t)(k0+rr)*N + n0 + c];
  __syncthreads();
  for (int rr = r; rr < 32; rr += 8) {
    int nr = n0 + rr;
    int np = (nr < 512) ? (nr*2) : ((nr-512)*2 + 1);
    wt[(size_t)np*K + k0 + c] = f2b(tile[c][rr]);
  }
}

// ---- dw conv weight transpose: w f32 [512][31] -> wdt f32 [31][512]
__global__ void k_dwt(const float* __restrict__ w, float* __restrict__ wdt) {
  int idx = blockIdx.x*256 + threadIdx.x;
  if (idx < 31*512) {
    int k = idx >> 9, d = idx & 511;
    wdt[idx] = w[d*31 + k];
  }
}

// ---- x f32 [B,D,T] -> s0 f32 [B,T,D] + bf16 copy
__global__ __launch_bounds__(256) void k_xin(const float* __restrict__ x, float* __restrict__ sf, u16* __restrict__ sb) {
  __shared__ float tile[32][33];
  int b = blockIdx.z;
  int d0 = blockIdx.y * 32;
  int t0 = blockIdx.x * 32;
  int c = threadIdx.x & 31, r = threadIdx.x >> 5;
  for (int rr = r; rr < 32; rr += 8)
    tile[rr][c] = x[((size_t)(b*D_ + d0 + rr))*T_ + t0 + c];
  __syncthreads();
  for (int rr = r; rr < 32; rr += 8) {
    float v = tile[c][rr];
    size_t o = ((size_t)(b*T_ + t0 + rr))*D_ + d0 + c;
    sf[o] = v; sb[o] = f2b(v);
  }
}

// ---- final: s f32 [B,T,D] -> out f32 [B,D,T]
__global__ __launch_bounds__(256) void k_transpose_out(const float* __restrict__ s, float* __restrict__ o) {
  __shared__ float tile[32][33];
  int b = blockIdx.z;
  int t0 = blockIdx.y * 32;
  int d0 = blockIdx.x * 32;
  int c = threadIdx.x & 31, r = threadIdx.x >> 5;
  for (int rr = r; rr < 32; rr += 8)
    tile[rr][c] = s[((size_t)(b*T_ + t0 + rr))*D_ + d0 + c];
  __syncthreads();
  for (int rr = r; rr < 32; rr += 8)
    o[((size_t)(b*D_ + d0 + rr))*T_ + t0 + c] = tile[c][rr];
}

// ---- MFMA GEMM: C[M,N] = epi(A[M,K]bf16 @ Wt[N,K]bf16^T + bias)
// epilogue modes: act(gelu), res+scale, f32/bf16 out, qkv scatter, fused GLU, GN partials
__global__ __launch_bounds__(256) void k_gemm_mfma(
    const u16* __restrict__ A, const u16* __restrict__ Wt,
    const float* __restrict__ bias, const float* __restrict__ res, float rscale,
    float* __restrict__ outf, u16* __restrict__ outb,
    u16* __restrict__ qd, u16* __restrict__ kd, u16* __restrict__ vd,
    u16* __restrict__ glub, float2* __restrict__ gnp,
    int M, int N, int K, int act)
{
  __shared__ u16 Ab[128*64];
  __shared__ u16 Bb[128*64];
  int tid = threadIdx.x;
  int w = tid >> 6, lane = tid & 63;
  int lr = lane & 15, lk = lane >> 4;
  int wm = w >> 1, wn = w & 1;
  int m0 = blockIdx.y * 128, n0 = blockIdx.x * 128;
  f32x4 acc[4][4] = {};

  for (int kt = 0; kt < K; kt += 64) {
    #pragma unroll
    for (int i = 0; i < 4; ++i) {
      int slot = (w*4 + i)*64 + lane;
      int r = slot >> 3, sc = slot & 7;
      int cc = sc ^ (r & 7);
      gl_lds16(A  + (size_t)(m0 + r)*K + kt + cc*8, (char*)Ab + (size_t)(w*4+i)*1024);
      gl_lds16(Wt + (size_t)(n0 + r)*K + kt + cc*8, (char*)Bb + (size_t)(w*4+i)*1024);
    }
    __syncthreads();
    #pragma unroll
    for (int ks = 0; ks < 2; ++ks) {
      s16x8 af[4], bfv[4];
      #pragma unroll
      for (int m = 0; m < 4; ++m) {
        int r = wm*64 + m*16 + lr;
        int sl = (ks*4 + lk) ^ (r & 7);
        af[m] = *(const s16x8*)(Ab + r*64 + sl*8);
      }
      #pragma unroll
      for (int n = 0; n < 4; ++n) {
        int r = wn*64 + n*16 + lr;
        int sl = (ks*4 + lk) ^ (r & 7);
        bfv[n] = *(const s16x8*)(Bb + r*64 + sl*8);
      }
      #pragma unroll
      for (int m = 0; m < 4; ++m)
        #pragma unroll
        for (int n = 0; n < 4; ++n)
          acc[m][n] = __builtin_amdgcn_mfma_f32_16x16x32_bf16(af[m], bfv[n], acc[m][n], 0, 0, 0);
    }
    __syncthreads();
  }

  float psum = 0.f, psq = 0.f;
  #pragma unroll
  for (int m = 0; m < 4; ++m) {
    #pragma unroll
    for (int n = 0; n < 4; ++n) {
      #pragma unroll
      for (int r2 = 0; r2 < 4; ++r2) {
        int row = m0 + wm*64 + m*16 + lk*4 + r2;
        int col = n0 + wn*64 + n*16 + lr;
        if (glub) {
          // col is interleaved index: even=a(half0), odd=b(half1)
          float vv = acc[m][n][r2] + bias[(col&1)*512 + (col>>1)];
          float pv = __shfl_xor(vv, 1);
          if ((col & 1) == 0)
            glub[(size_t)row*512 + (col>>1)] = f2b(vv * sigm(pv));
        } else {
          float vv = acc[m][n][r2] + bias[col];
          if (act) vv = gelu_exact(vv);
          size_t off = (size_t)row * N + col;
          if (res)  vv = res[off] + rscale * vv;
          if (outf) outf[off] = vv;
          if (outb) outb[off] = f2b(vv);
          if (qd) {
            int part = col >> 9, h = (col >> 6) & 7, dh = col & 63;
            int b = row >> 10, t = row & (T_-1);
            u16* dst = part == 0 ? qd : (part == 1 ? kd : vd);
            dst[(((size_t)(b*H_ + h))*T_ + t)*64 + dh] = f2b(vv);
          }
          psum += vv; psq += vv*vv;
        }
      }
    }
  }
  if (gnp) {
    float* r1 = (float*)Ab;
    float* r2s = (float*)Bb;
    __syncthreads();
    r1[tid] = psum; r2s[tid] = psq;
    __syncthreads();
    for (int off = 128; off; off >>= 1) {
      if (tid < off) { r1[tid] += r1[tid+off]; r2s[tid] += r2s[tid+off]; }
      __syncthreads();
    }
    if (tid == 0) {
      int bb = m0 >> 10;
      int idx = bb*32 + ((m0 >> 7) & 7)*4 + (n0 >> 7);   // N==512 layout
      gnp[idx] = make_float2(r1[0], r2s[0]);
    }
  }
}

// ---- per-head Toeplitz bias table: rbg[h][j] = rel_embed[bucket(j-1023)][h]
__global__ void k_rb(const float* __restrict__ rel_embed, float* __restrict__ rbg) {
  int idx = blockIdx.x*256 + threadIdx.x;    // 8*2048
  int h = idx >> 11, j = idx & 2047;
  if (j >= 2047) { rbg[idx] = 0.f; return; }
  int rel = j - 1023;
  int sign = rel >= 0 ? 1 : 0;
  int a = rel >= 0 ? rel : -rel;
  int bkt;
  if (a < 80) bkt = a;
  else {
    float lr = logf((float)a / 80.f) / 2.30258509299404568402f;
    int lp = 80 + (int)(lr * 80.f);
    bkt = lp < 159 ? lp : 159;
  }
  bkt += sign*160;
  rbg[idx] = rel_embed[bkt*H_ + h];
}

// ---- V transpose: vb bf16 [B,H,T,64] -> vtb bf16 [B,H,64,T]
__global__ __launch_bounds__(256) void k_vt(const u16* __restrict__ vb, u16* __restrict__ vtb) {
  __shared__ u16 tl[64][65];
  int blk = blockIdx.x;
  int tt0 = (blk & 15) * 64;
  size_t bh = (size_t)(blk >> 4);
  int tid = threadIdx.x;
  #pragma unroll
  for (int i = 0; i < 4; ++i) {
    int idx = i*256 + tid;
    int t = idx >> 4, d0 = (idx & 15) * 4;
    *(ushort4*)&tl[t][d0] = *(const ushort4*)(vb + (bh*T_ + tt0 + t)*64 + d0);
  }
  __syncthreads();
  #pragma unroll
  for (int i = 0; i < 4; ++i) {
    int idx = i*256 + tid;
    int dh = idx >> 4, t4 = (idx & 15) * 4;
    ushort4 o;
    o.x = tl[t4+0][dh]; o.y = tl[t4+1][dh]; o.z = tl[t4+2][dh]; o.w = tl[t4+3][dh];
    *(ushort4*)(vtb + (bh*64 + dh)*T_ + tt0 + t4) = o;
  }
}

// ---- MFMA flash attention: block=(b,h,64-q tile), 4 waves
__global__ __launch_bounds__(256) void k_attn3(
    const u16* __restrict__ qb, const u16* __restrict__ kb, const u16* __restrict__ vtb,
    const float* __restrict__ rbg,
    const float* __restrict__ gu, const float* __restrict__ gw, const float* __restrict__ gs,
    u16* __restrict__ outb)
{
  __shared__ u16 Kl[64*64];
  __shared__ u16 Vtl[64*64];
  __shared__ u16 Pl[64*64];
  __shared__ float rb[2048];
  __shared__ float cf[64];
  int blk = blockIdx.x;
  int qt = blk & 15;
  int h  = (blk >> 4) & 7;
  int b  = blk >> 7;
  int tid = threadIdx.x;
  int w = tid >> 6, lane = tid & 63;
  int lr = lane & 15, lk = lane >> 4;
  int g = lane >> 4;
  int t0 = qt * 64;
  size_t bh = (size_t)(b*H_ + h);

  for (int j = tid; j < 2048; j += 256) rb[j] = rbg[h*2048 + j];
  if (tid < 64) {
    const u16* qrow = qb + (bh*T_ + t0 + tid)*64;
    float vu = 0.f, vw = 0.f;
    for (int kk2 = 0; kk2 < 64; ++kk2) {
      float qv = b2f(qrow[kk2]);
      vu += qv * gu[h*64+kk2];
      vw += qv * gw[h*64+kk2];
    }
    float g1 = sigm(vu), g2 = sigm(vw);
    cf[tid] = 1.f + g1 + (1.f-g1)*gs[h]*g2;
  }
  const u16* qbase = qb + (bh*T_ + t0 + w*16 + lr)*64;
  s16x8 qa0 = *(const s16x8*)(qbase + lk*8);
  s16x8 qa1 = *(const s16x8*)(qbase + 32 + lk*8);

  f32x4 O[4] = {};
  float mcur[4] = {-1e30f,-1e30f,-1e30f,-1e30f};
  float lsum[4] = {0.f,0.f,0.f,0.f};
  const f32x4 zero = {0.f,0.f,0.f,0.f};
  __syncthreads();

  for (int kt = 0; kt < 16; ++kt) {
    #pragma unroll
    for (int i = 0; i < 2; ++i) {
      int slot = (i*4 + w)*64 + lane;
      int r = slot >> 3, scc = slot & 7;
      int cc = scc ^ (r & 7);
      gl_lds16(kb  + (bh*T_ + kt*64 + r)*64 + cc*8, (char*)Kl  + (i*4+w)*1024);
      gl_lds16(vtb + (bh*64 + r)*T_ + kt*64 + cc*8, (char*)Vtl + (i*4+w)*1024);
    }
    __syncthreads();
    f32x4 sc[4];
    #pragma unroll
    for (int n = 0; n < 4; ++n) {
      int row = n*16 + lr;
      int c0 = (0*4 + lk) ^ (row & 7);
      int c1 = (1*4 + lk) ^ (row & 7);
      s16x8 kb0 = *(const s16x8*)(Kl + row*64 + c0*8);
      s16x8 kb1 = *(const s16x8*)(Kl + row*64 + c1*8);
      f32x4 t = __builtin_amdgcn_mfma_f32_16x16x32_bf16(qa0, kb0, zero, 0, 0, 0);
      sc[n]   = __builtin_amdgcn_mfma_f32_16x16x32_bf16(qa1, kb1, t, 0, 0, 0);
    }
    float tmax[4];
    #pragma unroll
    for (int r2 = 0; r2 < 4; ++r2) {
      int q_local = w*16 + g*4 + r2;
      float cfv = cf[q_local];
      int qabs = t0 + q_local;
      float mx = -1e30f;
      #pragma unroll
      for (int n = 0; n < 4; ++n) {
        int sabs = kt*64 + n*16 + lr;
        float v = sc[n][r2]*0.125f + cfv * rb[sabs - qabs + 1023];
        sc[n][r2] = v;
        mx = fmaxf(mx, v);
      }
      tmax[r2] = mx;
    }
    #pragma unroll
    for (int mk = 1; mk < 16; mk <<= 1)
      #pragma unroll
      for (int r2 = 0; r2 < 4; ++r2)
        tmax[r2] = fmaxf(tmax[r2], __shfl_xor(tmax[r2], mk));
    float scl[4], psum[4];
    #pragma unroll
    for (int r2 = 0; r2 < 4; ++r2) {
      float mnew = fmaxf(mcur[r2], tmax[r2]);
      scl[r2] = __expf(mcur[r2] - mnew);
      mcur[r2] = mnew;
      int q_local = w*16 + g*4 + r2;
      float ps = 0.f;
      #pragma unroll
      for (int n = 0; n < 4; ++n) {
        float e = __expf(sc[n][r2] - mnew);
        ps += e;
        int s_local = n*16 + lr;
        Pl[q_local*64 + (((s_local>>3) ^ (q_local&7))<<3) + (s_local&7)] = f2b(e);
      }
      psum[r2] = ps;
    }
    #pragma unroll
    for (int mk = 1; mk < 16; mk <<= 1)
      #pragma unroll
      for (int r2 = 0; r2 < 4; ++r2)
        psum[r2] += __shfl_xor(psum[r2], mk);
    #pragma unroll
    for (int r2 = 0; r2 < 4; ++r2) lsum[r2] = lsum[r2]*scl[r2] + psum[r2];
    #pragma unroll
    for (int n = 0; n < 4; ++n)
      #pragma unroll
      for (int r2 = 0; r2 < 4; ++r2)
        O[n][r2] *= scl[r2];
    __syncthreads();
    int qrow = w*16 + lr;
    int pc0 = (0*4 + lk) ^ (qrow & 7), pc1 = (1*4 + lk) ^ (qrow & 7);
    s16x8 pa0 = *(const s16x8*)(Pl + qrow*64 + pc0*8);
    s16x8 pa1 = *(const s16x8*)(Pl + qrow*64 + pc1*8);
    #pragma unroll
    for (int n = 0; n < 4; ++n) {
      int dh = n*16 + lr;
      int c0 = (0*4 + lk) ^ (dh & 7), c1 = (1*4 + lk) ^ (dh & 7);
      s16x8 vb0 = *(const s16x8*)(Vtl + dh*64 + c0*8);
      s16x8 vb1 = *(const s16x8*)(Vtl + dh*64 + c1*8);
      O[n] = __builtin_amdgcn_mfma_f32_16x16x32_bf16(pa0, vb0, O[n], 0, 0, 0);
      O[n] = __builtin_amdgcn_mfma_f32_16x16x32_bf16(pa1, vb1, O[n], 0, 0, 0);
    }
    __syncthreads();
  }
  float inv[4];
  #pragma unroll
  for (int r2 = 0; r2 < 4; ++r2) inv[r2] = 1.f / lsum[r2];
  #pragma unroll
  for (int n = 0; n < 4; ++n)
    #pragma unroll
    for (int r2 = 0; r2 < 4; ++r2) {
      int q = t0 + w*16 + g*4 + r2;
      int dh = n*16 + lr;
      outb[((size_t)(b*T_) + q)*512 + h*64 + dh] = f2b(O[n][r2]*inv[r2]);
    }
}

// ---- depthwise conv: thread = 1 channel x 16 outputs, register sliding window
// input glub bf16 [B*T,512]; output f32 + per-block GN partials
__global__ __launch_bounds__(256) void k_dwconv2(
    const u16* __restrict__ g, const float* __restrict__ wdt,
    const float* __restrict__ bias, float* __restrict__ o, float2* __restrict__ part)
{
  int b = blockIdx.z, tg = blockIdx.y;
  int ch = blockIdx.x*256 + threadIdx.x;
  int t0 = tg*16;
  float wk[31];
  #pragma unroll
  for (int k = 0; k < 31; ++k) wk[k] = wdt[k*512 + ch];
  float win[46];
  const u16* gb = g + ((size_t)b*T_)*512 + ch;
  #pragma unroll
  for (int j = 0; j < 46; ++j) {
    int tt = t0 + j - 15;
    win[j] = (tt >= 0 && tt < T_) ? b2f(gb[(size_t)tt*512]) : 0.f;
  }
  float bv = bias[ch];
  float bsum = 0.f, bsq = 0.f;
  float* ob = o + ((size_t)b*T_ + t0)*512 + ch;
  #pragma unroll
  for (int j = 0; j < 16; ++j) {
    float acc = bv;
    #pragma unroll
    for (int k = 0; k < 31; ++k) acc += win[j+k]*wk[k];
    ob[(size_t)j*512] = acc;
    bsum += acc; bsq += acc*acc;
  }
  __shared__ float rs[256], rq[256];
  rs[threadIdx.x] = bsum; rq[threadIdx.x] = bsq; __syncthreads();
  for (int off = 128; off; off >>= 1) {
    if (threadIdx.x < off) { rs[threadIdx.x] += rs[threadIdx.x+off]; rq[threadIdx.x] += rq[threadIdx.x+off]; }
    __syncthreads();
  }
  if (threadIdx.x == 0) part[b*128 + tg*2 + blockIdx.x] = make_float2(rs[0], rq[0]);
}

__global__ void k_gn_final(const float2* __restrict__ part, float2* __restrict__ stats, int n) {
  int b = blockIdx.x;
  float s = 0.f, s2 = 0.f;
  for (int i = threadIdx.x; i < n; i += 64) {
    float2 p = part[b*n + i];
    s += p.x; s2 += p.y;
  }
  for (int off = 32; off; off >>= 1) { s += __shfl_down(s, off); s2 += __shfl_down(s2, off); }
  if (threadIdx.x == 0) {
    float cnt = (float)(D_*T_);
    float mean = s/cnt;
    float var = s2/cnt - mean*mean;
    stats[b] = make_float2(mean, rsqrtf(var + 1e-5f));
  }
}

__global__ void k_gn_apply(const float* __restrict__ x, const float2* __restrict__ stats,
                           const float* __restrict__ g, const float* __restrict__ bta,
                           u16* __restrict__ o, int silu_flag)
{
  size_t idx = (size_t)blockIdx.x*256 + threadIdx.x;
  int dd = idx & (D_-1);
  int b = (int)(idx >> 19);
  float2 st = stats[b];
  float v = (x[idx]-st.x)*st.y*g[dd] + bta[dd];
  if (silu_flag) v = v*sigm(v);
  o[idx] = f2b(v);
}

extern "C" void kernel_launch(void* const* d_in, const int* in_sizes, int n_in,
                              void* d_out, int out_size, void* d_ws, size_t ws_size,
                              hipStream_t stream)
{
  const float* x      = (const float*)d_in[0];
  const float* ff1_w1 = (const float*)d_in[1];
  const float* ff1_b1 = (const float*)d_in[2];
  const float* ff1_w2 = (const float*)d_in[3];
  const float* ff1_b2 = (const float*)d_in[4];
  const float* qkv_w  = (const float*)d_in[5];
  const float* qkv_b  = (const float*)d_in[6];
  const float* out_w  = (const float*)d_in[7];
  const float* out_b  = (const float*)d_in[8];
  const float* gn1_g  = (const float*)d_in[9];
  const float* gn1_b  = (const float*)d_in[10];
  const float* pw1_w  = (const float*)d_in[11];
  const float* pw1_b  = (const float*)d_in[12];
  const float* dw_w   = (const float*)d_in[13];
  const float* dw_b   = (const float*)d_in[14];
  const float* gn2_g  = (const float*)d_in[15];
  const float* gn2_b  = (const float*)d_in[16];
  const float* pw2_w  = (const float*)d_in[17];
  const float* pw2_b  = (const float*)d_in[18];
  const float* ff2_w1 = (const float*)d_in[19];
  const float* ff2_b1 = (const float*)d_in[20];
  const float* ff2_w2 = (const float*)d_in[21];
  const float* ff2_b2 = (const float*)d_in[22];
  const float* rel_embed = (const float*)d_in[23];
  const float* gate_u = (const float*)d_in[24];
  const float* gate_w = (const float*)d_in[25];
  const float* gate_scale = (const float*)d_in[26];

  char* ws = (char*)d_ws;
  const size_t MB = (size_t)1 << 20;
  float* s0f  = (float*)(ws + 0*MB);
  u16*   s0b  = (u16*)  (ws + 8*MB);
  u16*   h1b  = (u16*)  (ws + 12*MB);
  float* Sf   = (float*)(ws + 28*MB);
  u16*   Sb   = (u16*)  (ws + 36*MB);
  u16*   qbb  = (u16*)  (ws + 40*MB);
  u16*   kbb  = (u16*)  (ws + 44*MB);
  u16*   vbb  = (u16*)  (ws + 48*MB);
  u16*   vtb  = (u16*)  (ws + 52*MB);
  // aliases
  float* S2f  = (float*)(ws + 0*MB);
  u16*   attb = (u16*)  (ws + 8*MB);
  u16*   gn1b = (u16*)  (ws + 36*MB);
  u16*   glub = (u16*)  (ws + 56*MB);   // [M,512] bf16
  float* dcf  = (float*)(ws + 28*MB);
  u16*   gn2b = (u16*)  (ws + 36*MB);
  float* S3f  = (float*)(ws + 40*MB);
  u16*   S3b  = (u16*)  (ws + 48*MB);
  u16*   h3b  = (u16*)  (ws + 12*MB);
  float* Sout = (float*)(ws + 28*MB);
  // weights bf16
  u16* ff1w1t = (u16*)(ws + 64*MB);
  u16* ff1w2t = (u16*)(ws + 66*MB);
  u16* qkvt   = (u16*)(ws + 68*MB);
  u16* outt   = (u16*)(ws + 70*MB);
  u16* pw1t   = (u16*)(ws + 72*MB);
  u16* pw2t   = (u16*)(ws + 74*MB);
  u16* ff2w1t = (u16*)(ws + 76*MB);
  u16* ff2w2t = (u16*)(ws + 78*MB);
  float* rbg  = (float*)(ws + 80*MB);
  float* wdt  = (float*)(ws + 81*MB);   // [31][512] f32
  float2* part1 = (float2*)(ws + 84*MB);
  float2* part2 = (float2*)(ws + 84*MB + 8192);
  float2* st1   = (float2*)(ws + 84*MB + 16384);
  float2* st2   = (float2*)(ws + 84*MB + 16384 + 64);

  const int M = B_*T_;
  dim3 blk(256);

  k_wt<<<dim3(FFD/32, D_/32), blk, 0, stream>>>(ff1_w1, ff1w1t, D_, FFD);
  k_wt<<<dim3(D_/32, FFD/32), blk, 0, stream>>>(ff1_w2, ff1w2t, FFD, D_);
  k_wt<<<dim3(1536/32, D_/32), blk, 0, stream>>>(qkv_w, qkvt, D_, 1536);
  k_wt<<<dim3(D_/32, D_/32), blk, 0, stream>>>(out_w, outt, D_, D_);
  k_wt_glu<<<dim3(1024/32, D_/32), blk, 0, stream>>>(pw1_w, pw1t, D_, 1024);
  k_wt<<<dim3(D_/32, D_/32), blk, 0, stream>>>(pw2_w, pw2t, D_, D_);
  k_wt<<<dim3(FFD/32, D_/32), blk, 0, stream>>>(ff2_w1, ff2w1t, D_, FFD);
  k_wt<<<dim3(D_/32, FFD/32), blk, 0, stream>>>(ff2_w2, ff2w2t, FFD, D_);
  k_rb<<<dim3(64), blk, 0, stream>>>(rel_embed, rbg);
  k_dwt<<<dim3(62), blk, 0, stream>>>(dw_w, wdt);

  k_xin<<<dim3(T_/32, D_/32, B_), blk, 0, stream>>>(x, s0f, s0b);

  // FFN1
  k_gemm_mfma<<<dim3(FFD/128, M/128), blk, 0, stream>>>(s0b, ff1w1t, ff1_b1, nullptr, 0.f,
      nullptr, h1b, nullptr, nullptr, nullptr, nullptr, nullptr, M, FFD, D_, 1);
  k_gemm_mfma<<<dim3(D_/128, M/128), blk, 0, stream>>>(h1b, ff1w2t, ff1_b2, s0f, 0.5f,
      Sf, Sb, nullptr, nullptr, nullptr, nullptr, nullptr, M, D_, FFD, 0);
  // QKV
  k_gemm_mfma<<<dim3(1536/128, M/128), blk, 0, stream>>>(Sb, qkvt, qkv_b, nullptr, 0.f,
      nullptr, nullptr, qbb, kbb, vbb, nullptr, nullptr, M, 1536, D_, 0);
  k_vt<<<dim3(B_*H_*16), blk, 0, stream>>>(vbb, vtb);
  k_attn3<<<dim3(B_*H_*16), blk, 0, stream>>>(qbb, kbb, vtb, rbg, gate_u, gate_w, gate_scale, attb);
  // out proj + residual + GN1 partials
  k_gemm_mfma<<<dim3(D_/128, M/128), blk, 0, stream>>>(attb, outt, out_b, Sf, 1.f,
      S2f, nullptr, nullptr, nullptr, nullptr, nullptr, part1, M, D_, D_, 0);
  k_gn_final<<<dim3(B_), dim3(64), 0, stream>>>(part1, st1, 32);
  k_gn_apply<<<dim3((M*D_)/256), blk, 0, stream>>>(S2f, st1, gn1_g, gn1_b, gn1b, 0);
  // pw1 + fused GLU
  k_gemm_mfma<<<dim3(1024/128, M/128), blk, 0, stream>>>(gn1b, pw1t, pw1_b, nullptr, 0.f,
      nullptr, nullptr, nullptr, nullptr, nullptr, glub, nullptr, M, 1024, D_, 0);
  // depthwise conv + GN2 partials
  k_dwconv2<<<dim3(2, T_/16, B_), blk, 0, stream>>>(glub, wdt, dw_b, dcf, part2);
  k_gn_final<<<dim3(B_), dim3(64), 0, stream>>>(part2, st2, 128);
  k_gn_apply<<<dim3((M*D_)/256), blk, 0, stream>>>(dcf, st2, gn2_g, gn2_b, gn2b, 1);
  k_gemm_mfma<<<dim3(D_/128, M/128), blk, 0, stream>>>(gn2b, pw2t, pw2_b, S2f, 1.f,
      S3f, S3b, nullptr, nullptr, nullptr, nullptr, nullptr, M, D_, D_, 0);
  // FFN2
  k_gemm_mfma<<<dim3(FFD/128, M/128), blk, 0, stream>>>(S3b, ff2w1t, ff2_b1, nullptr, 0.f,
      nullptr, h3b, nullptr, nullptr, nullptr, nullptr, nullptr, M, FFD, D_, 1);
  k_gemm_mfma<<<dim3(D_/128, M/128), blk, 0, stream>>>(h3b, ff2w2t, ff2_b2, S3f, 0.5f,
      Sout, nullptr, nullptr, nullptr, nullptr, nullptr, nullptr, M, D_, FFD, 0);
  k_transpose_out<<<dim3(D_/32, T_/32, B_), blk, 0, stream>>>(Sout, (float*)d_out);
}

// Round 11
// 439.308 us; speedup vs baseline: 9.5303x; 1.2523x over previous
//
#include <hip/hip_runtime.h>
#include <hip/hip_bf16.h>
#include <math.h>

#define B_ 4
#define D_ 512
#define T_ 1024
#define H_ 8
#define FFD 2048

typedef unsigned short u16;
typedef short s16x8 __attribute__((ext_vector_type(8)));
typedef float f32x4 __attribute__((ext_vector_type(4)));

__device__ inline float sigm(float x){ return 1.f/(1.f+expf(-x)); }
__device__ inline float gelu_exact(float x){ return 0.5f*x*(1.f+erff(x*0.70710678118654752440f)); }
__device__ inline u16 f2b(float f){
  __hip_bfloat16 h = __float2bfloat16(f);
  return *reinterpret_cast<u16*>(&h);
}
__device__ inline float b2f(u16 u){ return __uint_as_float(((unsigned)u)<<16); }

__device__ inline void gl_lds16(const void* g, void* l) {
  __builtin_amdgcn_global_load_lds(
      (const __attribute__((address_space(1))) void*)g,
      (__attribute__((address_space(3))) void*)l, 16, 0, 0);
}

// ---- weight transpose+cast: W f32 [K][N] -> Wt bf16 [N][K]
__global__ __launch_bounds__(256) void k_wt(const float* __restrict__ w, u16* __restrict__ wt, int K, int N) {
  __shared__ float tile[32][33];
  int n0 = blockIdx.x*32, k0 = blockIdx.y*32;
  int c = threadIdx.x & 31, r = threadIdx.x >> 5;
  for (int rr = r; rr < 32; rr += 8)
    tile[rr][c] = w[(size_t)(k0+rr)*N + n0 + c];
  __syncthreads();
  for (int rr = r; rr < 32; rr += 8)
    wt[(size_t)(n0+rr)*K + k0 + c] = f2b(tile[c][rr]);
}

// ---- pw1 weight: transpose+cast with GLU column interleave.
__global__ __launch_bounds__(256) void k_wt_glu(const float* __restrict__ w, u16* __restrict__ wt, int K, int N) {
  __shared__ float tile[32][33];
  int n0 = blockIdx.x*32, k0 = blockIdx.y*32;
  int c = threadIdx.x & 31, r = threadIdx.x >> 5;
  for (int rr = r; rr < 32; rr += 8)
    tile[rr][c] = w[(size_t)(k0+rr)*N + n0 + c];
  __syncthreads();
  for (int rr = r; rr < 32; rr += 8) {
    int nr = n0 + rr;
    int np = (nr < 512) ? (nr*2) : ((nr-512)*2 + 1);
    wt[(size_t)np*K + k0 + c] = f2b(tile[c][rr]);
  }
}

// ---- dw conv weight transpose: w f32 [512][31] -> wdt f32 [31][512]
__global__ void k_dwt(const float* __restrict__ w, float* __restrict__ wdt) {
  int idx = blockIdx.x*256 + threadIdx.x;
  if (idx < 31*512) {
    int k = idx >> 9, d = idx & 511;
    wdt[idx] = w[d*31 + k];
  }
}

// ---- x f32 [B,D,T] -> s0 f32 [B,T,D] + bf16 copy
__global__ __launch_bounds__(256) void k_xin(const float* __restrict__ x, float* __restrict__ sf, u16* __restrict__ sb) {
  __shared__ float tile[32][33];
  int b = blockIdx.z;
  int d0 = blockIdx.y * 32;
  int t0 = blockIdx.x * 32;
  int c = threadIdx.x & 31, r = threadIdx.x >> 5;
  for (int rr = r; rr < 32; rr += 8)
    tile[rr][c] = x[((size_t)(b*D_ + d0 + rr))*T_ + t0 + c];
  __syncthreads();
  for (int rr = r; rr < 32; rr += 8) {
    float v = tile[c][rr];
    size_t o = ((size_t)(b*T_ + t0 + rr))*D_ + d0 + c;
    sf[o] = v; sb[o] = f2b(v);
  }
}

// ---- final: s f32 [B,T,D] -> out f32 [B,D,T]
__global__ __launch_bounds__(256) void k_transpose_out(const float* __restrict__ s, float* __restrict__ o) {
  __shared__ float tile[32][33];
  int b = blockIdx.z;
  int t0 = blockIdx.y * 32;
  int d0 = blockIdx.x * 32;
  int c = threadIdx.x & 31, r = threadIdx.x >> 5;
  for (int rr = r; rr < 32; rr += 8)
    tile[rr][c] = s[((size_t)(b*T_ + t0 + rr))*D_ + d0 + c];
  __syncthreads();
  for (int rr = r; rr < 32; rr += 8)
    o[((size_t)(b*D_ + d0 + rr))*T_ + t0 + c] = tile[c][rr];
}

// ---- MFMA GEMM, BM x 128 tile (BM=64 or 128), BK=64, 4 waves (2x2).
// split-K mode (partf != null): K range = [z*kLen, z*kLen+kLen), raw acc -> partf[z]
template<int BM>
__global__ __launch_bounds__(256) void k_gemm_mfma(
    const u16* __restrict__ A, const u16* __restrict__ Wt,
    const float* __restrict__ bias, const float* __restrict__ res, float rscale,
    float* __restrict__ outf, u16* __restrict__ outb,
    u16* __restrict__ qd, u16* __restrict__ kd, u16* __restrict__ vd,
    u16* __restrict__ glub, float2* __restrict__ gnp, float* __restrict__ partf,
    int M, int N, int K, int kLen, int act)
{
  constexpr int MFR = BM/32;      // m-frags per wave (2 or 4)
  __shared__ u16 Ab[BM*64];
  __shared__ u16 Bb[128*64];
  int tid = threadIdx.x;
  int w = tid >> 6, lane = tid & 63;
  int lr = lane & 15, lk = lane >> 4;
  int wm = w >> 1, wn = w & 1;
  int m0 = blockIdx.y * BM, n0 = blockIdx.x * 128;
  int kbeg = partf ? blockIdx.z * kLen : 0;
  int kend = partf ? kbeg + kLen : K;
  f32x4 acc[MFR][4] = {};

  for (int kt = kbeg; kt < kend; kt += 64) {
    #pragma unroll
    for (int i = 0; i < MFR; ++i) {
      int slot = (w*MFR + i)*64 + lane;
      int r = slot >> 3, sc = slot & 7;
      int cc = sc ^ (r & 7);
      gl_lds16(A + (size_t)(m0 + r)*K + kt + cc*8, (char*)Ab + (size_t)(w*MFR+i)*1024);
    }
    #pragma unroll
    for (int i = 0; i < 4; ++i) {
      int slot = (w*4 + i)*64 + lane;
      int r = slot >> 3, sc = slot & 7;
      int cc = sc ^ (r & 7);
      gl_lds16(Wt + (size_t)(n0 + r)*K + kt + cc*8, (char*)Bb + (size_t)(w*4+i)*1024);
    }
    __syncthreads();
    #pragma unroll
    for (int ks = 0; ks < 2; ++ks) {
      s16x8 af[MFR], bfv[4];
      #pragma unroll
      for (int m = 0; m < MFR; ++m) {
        int r = wm*(BM/2) + m*16 + lr;
        int sl = (ks*4 + lk) ^ (r & 7);
        af[m] = *(const s16x8*)(Ab + r*64 + sl*8);
      }
      #pragma unroll
      for (int n = 0; n < 4; ++n) {
        int r = wn*64 + n*16 + lr;
        int sl = (ks*4 + lk) ^ (r & 7);
        bfv[n] = *(const s16x8*)(Bb + r*64 + sl*8);
      }
      #pragma unroll
      for (int m = 0; m < MFR; ++m)
        #pragma unroll
        for (int n = 0; n < 4; ++n)
          acc[m][n] = __builtin_amdgcn_mfma_f32_16x16x32_bf16(af[m], bfv[n], acc[m][n], 0, 0, 0);
    }
    __syncthreads();
  }

  if (partf) {
    float* pp = partf + (size_t)blockIdx.z * M * N;
    #pragma unroll
    for (int m = 0; m < MFR; ++m)
      #pragma unroll
      for (int n = 0; n < 4; ++n)
        #pragma unroll
        for (int r2 = 0; r2 < 4; ++r2) {
          int row = m0 + wm*(BM/2) + m*16 + lk*4 + r2;
          int col = n0 + wn*64 + n*16 + lr;
          pp[(size_t)row*N + col] = acc[m][n][r2];
        }
    return;
  }

  float psum = 0.f, psq = 0.f;
  #pragma unroll
  for (int m = 0; m < MFR; ++m) {
    #pragma unroll
    for (int n = 0; n < 4; ++n) {
      #pragma unroll
      for (int r2 = 0; r2 < 4; ++r2) {
        int row = m0 + wm*(BM/2) + m*16 + lk*4 + r2;
        int col = n0 + wn*64 + n*16 + lr;
        if (glub) {
          float vv = acc[m][n][r2] + bias[(col&1)*512 + (col>>1)];
          float pv = __shfl_xor(vv, 1);
          if ((col & 1) == 0)
            glub[(size_t)row*512 + (col>>1)] = f2b(vv * sigm(pv));
        } else {
          float vv = acc[m][n][r2] + bias[col];
          if (act) vv = gelu_exact(vv);
          size_t off = (size_t)row * N + col;
          if (res)  vv = res[off] + rscale * vv;
          if (outf) outf[off] = vv;
          if (outb) outb[off] = f2b(vv);
          if (qd) {
            int part = col >> 9, h = (col >> 6) & 7, dh = col & 63;
            int b = row >> 10, t = row & (T_-1);
            u16* dst = part == 0 ? qd : (part == 1 ? kd : vd);
            dst[(((size_t)(b*H_ + h))*T_ + t)*64 + dh] = f2b(vv);
          }
          psum += vv; psq += vv*vv;
        }
      }
    }
  }
  if (gnp) {
    float* r1 = (float*)Ab;
    float* r2s = (float*)Bb;
    __syncthreads();
    r1[tid] = psum; r2s[tid] = psq;
    __syncthreads();
    for (int off = 128; off; off >>= 1) {
      if (tid < off) { r1[tid] += r1[tid+off]; r2s[tid] += r2s[tid+off]; }
      __syncthreads();
    }
    if (tid == 0) {
      // N==512: per batch (1024 rows) there are (1024/BM) m-blocks x 4 n-blocks
      int bb = m0 >> 10;
      int mloc = (m0 >> (BM==64 ? 6 : 7)) & ((1024/BM) - 1);
      int idx = bb*(1024/BM)*4 + mloc*4 + (n0 >> 7);
      gnp[idx] = make_float2(r1[0], r2s[0]);
    }
  }
}

// ---- split-K combine: out = res + rscale*(p0+p1+bias), f32 + optional bf16
__global__ __launch_bounds__(256) void k_combine(
    const float4* __restrict__ p, const float* __restrict__ bias,
    const float4* __restrict__ res, float rscale,
    float4* __restrict__ outf, u16* __restrict__ outb)
{
  size_t i = (size_t)blockIdx.x*256 + threadIdx.x;   // over M*128 float4s
  int c4 = (i & 127) << 2;
  float4 a = p[i];
  float4 b = p[i + (size_t)(B_*T_)*128];
  float4 bs = *(const float4*)(bias + c4);
  float4 r = res[i];
  float4 v;
  v.x = r.x + rscale*(a.x + b.x + bs.x);
  v.y = r.y + rscale*(a.y + b.y + bs.y);
  v.z = r.z + rscale*(a.z + b.z + bs.z);
  v.w = r.w + rscale*(a.w + b.w + bs.w);
  if (outf) outf[i] = v;
  if (outb) {
    ushort4 u; u.x = f2b(v.x); u.y = f2b(v.y); u.z = f2b(v.z); u.w = f2b(v.w);
    *(ushort4*)(outb + i*4) = u;
  }
}

// ---- per-head Toeplitz bias table
__global__ void k_rb(const float* __restrict__ rel_embed, float* __restrict__ rbg) {
  int idx = blockIdx.x*256 + threadIdx.x;    // 8*2048
  int h = idx >> 11, j = idx & 2047;
  if (j >= 2047) { rbg[idx] = 0.f; return; }
  int rel = j - 1023;
  int sign = rel >= 0 ? 1 : 0;
  int a = rel >= 0 ? rel : -rel;
  int bkt;
  if (a < 80) bkt = a;
  else {
    float lr = logf((float)a / 80.f) / 2.30258509299404568402f;
    int lp = 80 + (int)(lr * 80.f);
    bkt = lp < 159 ? lp : 159;
  }
  bkt += sign*160;
  rbg[idx] = rel_embed[bkt*H_ + h];
}

// ---- V transpose: vb bf16 [B,H,T,64] -> vtb bf16 [B,H,64,T]
__global__ __launch_bounds__(256) void k_vt(const u16* __restrict__ vb, u16* __restrict__ vtb) {
  __shared__ u16 tl[64][65];
  int blk = blockIdx.x;
  int tt0 = (blk & 15) * 64;
  size_t bh = (size_t)(blk >> 4);
  int tid = threadIdx.x;
  #pragma unroll
  for (int i = 0; i < 4; ++i) {
    int idx = i*256 + tid;
    int t = idx >> 4, d0 = (idx & 15) * 4;
    *(ushort4*)&tl[t][d0] = *(const ushort4*)(vb + (bh*T_ + tt0 + t)*64 + d0);
  }
  __syncthreads();
  #pragma unroll
  for (int i = 0; i < 4; ++i) {
    int idx = i*256 + tid;
    int dh = idx >> 4, t4 = (idx & 15) * 4;
    ushort4 o;
    o.x = tl[t4+0][dh]; o.y = tl[t4+1][dh]; o.z = tl[t4+2][dh]; o.w = tl[t4+3][dh];
    *(ushort4*)(vtb + (bh*64 + dh)*T_ + tt0 + t4) = o;
  }
}

// ---- MFMA flash attention
__global__ __launch_bounds__(256) void k_attn3(
    const u16* __restrict__ qb, const u16* __restrict__ kb, const u16* __restrict__ vtb,
    const float* __restrict__ rbg,
    const float* __restrict__ gu, const float* __restrict__ gw, const float* __restrict__ gs,
    u16* __restrict__ outb)
{
  __shared__ u16 Kl[64*64];
  __shared__ u16 Vtl[64*64];
  __shared__ u16 Pl[64*64];
  __shared__ float rb[2048];
  __shared__ float cf[64];
  int blk = blockIdx.x;
  int qt = blk & 15;
  int h  = (blk >> 4) & 7;
  int b  = blk >> 7;
  int tid = threadIdx.x;
  int w = tid >> 6, lane = tid & 63;
  int lr = lane & 15, lk = lane >> 4;
  int g = lane >> 4;
  int t0 = qt * 64;
  size_t bh = (size_t)(b*H_ + h);

  for (int j = tid; j < 2048; j += 256) rb[j] = rbg[h*2048 + j];
  if (tid < 64) {
    const u16* qrow = qb + (bh*T_ + t0 + tid)*64;
    float vu = 0.f, vw = 0.f;
    for (int kk2 = 0; kk2 < 64; ++kk2) {
      float qv = b2f(qrow[kk2]);
      vu += qv * gu[h*64+kk2];
      vw += qv * gw[h*64+kk2];
    }
    float g1 = sigm(vu), g2 = sigm(vw);
    cf[tid] = 1.f + g1 + (1.f-g1)*gs[h]*g2;
  }
  const u16* qbase = qb + (bh*T_ + t0 + w*16 + lr)*64;
  s16x8 qa0 = *(const s16x8*)(qbase + lk*8);
  s16x8 qa1 = *(const s16x8*)(qbase + 32 + lk*8);

  f32x4 O[4] = {};
  float mcur[4] = {-1e30f,-1e30f,-1e30f,-1e30f};
  float lsum[4] = {0.f,0.f,0.f,0.f};
  const f32x4 zero = {0.f,0.f,0.f,0.f};
  __syncthreads();

  for (int kt = 0; kt < 16; ++kt) {
    #pragma unroll
    for (int i = 0; i < 2; ++i) {
      int slot = (i*4 + w)*64 + lane;
      int r = slot >> 3, scc = slot & 7;
      int cc = scc ^ (r & 7);
      gl_lds16(kb  + (bh*T_ + kt*64 + r)*64 + cc*8, (char*)Kl  + (i*4+w)*1024);
      gl_lds16(vtb + (bh*64 + r)*T_ + kt*64 + cc*8, (char*)Vtl + (i*4+w)*1024);
    }
    __syncthreads();
    f32x4 sc[4];
    #pragma unroll
    for (int n = 0; n < 4; ++n) {
      int row = n*16 + lr;
      int c0 = (0*4 + lk) ^ (row & 7);
      int c1 = (1*4 + lk) ^ (row & 7);
      s16x8 kb0 = *(const s16x8*)(Kl + row*64 + c0*8);
      s16x8 kb1 = *(const s16x8*)(Kl + row*64 + c1*8);
      f32x4 t = __builtin_amdgcn_mfma_f32_16x16x32_bf16(qa0, kb0, zero, 0, 0, 0);
      sc[n]   = __builtin_amdgcn_mfma_f32_16x16x32_bf16(qa1, kb1, t, 0, 0, 0);
    }
    float tmax[4];
    #pragma unroll
    for (int r2 = 0; r2 < 4; ++r2) {
      int q_local = w*16 + g*4 + r2;
      float cfv = cf[q_local];
      int qabs = t0 + q_local;
      float mx = -1e30f;
      #pragma unroll
      for (int n = 0; n < 4; ++n) {
        int sabs = kt*64 + n*16 + lr;
        float v = sc[n][r2]*0.125f + cfv * rb[sabs - qabs + 1023];
        sc[n][r2] = v;
        mx = fmaxf(mx, v);
      }
      tmax[r2] = mx;
    }
    #pragma unroll
    for (int mk = 1; mk < 16; mk <<= 1)
      #pragma unroll
      for (int r2 = 0; r2 < 4; ++r2)
        tmax[r2] = fmaxf(tmax[r2], __shfl_xor(tmax[r2], mk));
    float scl[4], psum[4];
    #pragma unroll
    for (int r2 = 0; r2 < 4; ++r2) {
      float mnew = fmaxf(mcur[r2], tmax[r2]);
      scl[r2] = __expf(mcur[r2] - mnew);
      mcur[r2] = mnew;
      int q_local = w*16 + g*4 + r2;
      float ps = 0.f;
      #pragma unroll
      for (int n = 0; n < 4; ++n) {
        float e = __expf(sc[n][r2] - mnew);
        ps += e;
        int s_local = n*16 + lr;
        Pl[q_local*64 + (((s_local>>3) ^ (q_local&7))<<3) + (s_local&7)] = f2b(e);
      }
      psum[r2] = ps;
    }
    #pragma unroll
    for (int mk = 1; mk < 16; mk <<= 1)
      #pragma unroll
      for (int r2 = 0; r2 < 4; ++r2)
        psum[r2] += __shfl_xor(psum[r2], mk);
    #pragma unroll
    for (int r2 = 0; r2 < 4; ++r2) lsum[r2] = lsum[r2]*scl[r2] + psum[r2];
    #pragma unroll
    for (int n = 0; n < 4; ++n)
      #pragma unroll
      for (int r2 = 0; r2 < 4; ++r2)
        O[n][r2] *= scl[r2];
    __syncthreads();
    int qrow = w*16 + lr;
    int pc0 = (0*4 + lk) ^ (qrow & 7), pc1 = (1*4 + lk) ^ (qrow & 7);
    s16x8 pa0 = *(const s16x8*)(Pl + qrow*64 + pc0*8);
    s16x8 pa1 = *(const s16x8*)(Pl + qrow*64 + pc1*8);
    #pragma unroll
    for (int n = 0; n < 4; ++n) {
      int dh = n*16 + lr;
      int c0 = (0*4 + lk) ^ (dh & 7), c1 = (1*4 + lk) ^ (dh & 7);
      s16x8 vb0 = *(const s16x8*)(Vtl + dh*64 + c0*8);
      s16x8 vb1 = *(const s16x8*)(Vtl + dh*64 + c1*8);
      O[n] = __builtin_amdgcn_mfma_f32_16x16x32_bf16(pa0, vb0, O[n], 0, 0, 0);
      O[n] = __builtin_amdgcn_mfma_f32_16x16x32_bf16(pa1, vb1, O[n], 0, 0, 0);
    }
    __syncthreads();
  }
  float inv[4];
  #pragma unroll
  for (int r2 = 0; r2 < 4; ++r2) inv[r2] = 1.f / lsum[r2];
  #pragma unroll
  for (int n = 0; n < 4; ++n)
    #pragma unroll
    for (int r2 = 0; r2 < 4; ++r2) {
      int q = t0 + w*16 + g*4 + r2;
      int dh = n*16 + lr;
      outb[((size_t)(b*T_) + q)*512 + h*64 + dh] = f2b(O[n][r2]*inv[r2]);
    }
}

// ---- depthwise conv: thread = 1 channel x 16 outputs, register sliding window
__global__ __launch_bounds__(256) void k_dwconv2(
    const u16* __restrict__ g, const float* __restrict__ wdt,
    const float* __restrict__ bias, float* __restrict__ o, float2* __restrict__ part)
{
  int b = blockIdx.z, tg = blockIdx.y;
  int ch = blockIdx.x*256 + threadIdx.x;
  int t0 = tg*16;
  float wk[31];
  #pragma unroll
  for (int k = 0; k < 31; ++k) wk[k] = wdt[k*512 + ch];
  float win[46];
  const u16* gb = g + ((size_t)b*T_)*512 + ch;
  #pragma unroll
  for (int j = 0; j < 46; ++j) {
    int tt = t0 + j - 15;
    win[j] = (tt >= 0 && tt < T_) ? b2f(gb[(size_t)tt*512]) : 0.f;
  }
  float bv = bias[ch];
  float bsum = 0.f, bsq = 0.f;
  float* ob = o + ((size_t)b*T_ + t0)*512 + ch;
  #pragma unroll
  for (int j = 0; j < 16; ++j) {
    float acc = bv;
    #pragma unroll
    for (int k = 0; k < 31; ++k) acc += win[j+k]*wk[k];
    ob[(size_t)j*512] = acc;
    bsum += acc; bsq += acc*acc;
  }
  __shared__ float rs[256], rq[256];
  rs[threadIdx.x] = bsum; rq[threadIdx.x] = bsq; __syncthreads();
  for (int off = 128; off; off >>= 1) {
    if (threadIdx.x < off) { rs[threadIdx.x] += rs[threadIdx.x+off]; rq[threadIdx.x] += rq[threadIdx.x+off]; }
    __syncthreads();
  }
  if (threadIdx.x == 0) part[b*128 + tg*2 + blockIdx.x] = make_float2(rs[0], rq[0]);
}

__global__ void k_gn_final(const float2* __restrict__ part, float2* __restrict__ stats, int n) {
  int b = blockIdx.x;
  float s = 0.f, s2 = 0.f;
  for (int i = threadIdx.x; i < n; i += 64) {
    float2 p = part[b*n + i];
    s += p.x; s2 += p.y;
  }
  for (int off = 32; off; off >>= 1) { s += __shfl_down(s, off); s2 += __shfl_down(s2, off); }
  if (threadIdx.x == 0) {
    float cnt = (float)(D_*T_);
    float mean = s/cnt;
    float var = s2/cnt - mean*mean;
    stats[b] = make_float2(mean, rsqrtf(var + 1e-5f));
  }
}

__global__ void k_gn_apply(const float* __restrict__ x, const float2* __restrict__ stats,
                           const float* __restrict__ g, const float* __restrict__ bta,
                           u16* __restrict__ o, int silu_flag)
{
  size_t idx = (size_t)blockIdx.x*256 + threadIdx.x;
  int dd = idx & (D_-1);
  int b = (int)(idx >> 19);
  float2 st = stats[b];
  float v = (x[idx]-st.x)*st.y*g[dd] + bta[dd];
  if (silu_flag) v = v*sigm(v);
  o[idx] = f2b(v);
}

extern "C" void kernel_launch(void* const* d_in, const int* in_sizes, int n_in,
                              void* d_out, int out_size, void* d_ws, size_t ws_size,
                              hipStream_t stream)
{
  const float* x      = (const float*)d_in[0];
  const float* ff1_w1 = (const float*)d_in[1];
  const float* ff1_b1 = (const float*)d_in[2];
  const float* ff1_w2 = (const float*)d_in[3];
  const float* ff1_b2 = (const float*)d_in[4];
  const float* qkv_w  = (const float*)d_in[5];
  const float* qkv_b  = (const float*)d_in[6];
  const float* out_w  = (const float*)d_in[7];
  const float* out_b  = (const float*)d_in[8];
  const float* gn1_g  = (const float*)d_in[9];
  const float* gn1_b  = (const float*)d_in[10];
  const float* pw1_w  = (const float*)d_in[11];
  const float* pw1_b  = (const float*)d_in[12];
  const float* dw_w   = (const float*)d_in[13];
  const float* dw_b   = (const float*)d_in[14];
  const float* gn2_g  = (const float*)d_in[15];
  const float* gn2_b  = (const float*)d_in[16];
  const float* pw2_w  = (const float*)d_in[17];
  const float* pw2_b  = (const float*)d_in[18];
  const float* ff2_w1 = (const float*)d_in[19];
  const float* ff2_b1 = (const float*)d_in[20];
  const float* ff2_w2 = (const float*)d_in[21];
  const float* ff2_b2 = (const float*)d_in[22];
  const float* rel_embed = (const float*)d_in[23];
  const float* gate_u = (const float*)d_in[24];
  const float* gate_w = (const float*)d_in[25];
  const float* gate_scale = (const float*)d_in[26];

  char* ws = (char*)d_ws;
  const size_t MB = (size_t)1 << 20;
  float* s0f  = (float*)(ws + 0*MB);
  u16*   s0b  = (u16*)  (ws + 8*MB);
  u16*   h1b  = (u16*)  (ws + 12*MB);
  float* Sf   = (float*)(ws + 28*MB);
  u16*   Sb   = (u16*)  (ws + 36*MB);
  u16*   qbb  = (u16*)  (ws + 40*MB);
  u16*   kbb  = (u16*)  (ws + 44*MB);
  u16*   vbb  = (u16*)  (ws + 48*MB);
  u16*   vtb  = (u16*)  (ws + 52*MB);
  // aliases
  float* S2f  = (float*)(ws + 0*MB);
  u16*   attb = (u16*)  (ws + 8*MB);
  u16*   gn1b = (u16*)  (ws + 36*MB);
  u16*   glub = (u16*)  (ws + 56*MB);   // [M,512] bf16
  float* dcf  = (float*)(ws + 28*MB);
  u16*   gn2b = (u16*)  (ws + 36*MB);
  float* S3f  = (float*)(ws + 40*MB);
  u16*   S3b  = (u16*)  (ws + 48*MB);
  u16*   h3b  = (u16*)  (ws + 12*MB);
  float* Sout = (float*)(ws + 28*MB);
  float* PK1  = (float*)(ws + 40*MB);   // 16MB split-K partials (FFN1-2; qbb..vtb dead)
  float* PK2  = (float*)(ws + 48*MB);   // 16MB split-K partials (FFN2-2; S3b/vtb/glub dead)
  // weights bf16
  u16* ff1w1t = (u16*)(ws + 64*MB);
  u16* ff1w2t = (u16*)(ws + 66*MB);
  u16* qkvt   = (u16*)(ws + 68*MB);
  u16* outt   = (u16*)(ws + 70*MB);
  u16* pw1t   = (u16*)(ws + 72*MB);
  u16* pw2t   = (u16*)(ws + 74*MB);
  u16* ff2w1t = (u16*)(ws + 76*MB);
  u16* ff2w2t = (u16*)(ws + 78*MB);
  float* rbg  = (float*)(ws + 80*MB);
  float* wdt  = (float*)(ws + 81*MB);
  float2* part1 = (float2*)(ws + 84*MB);
  float2* part2 = (float2*)(ws + 84*MB + 8192);
  float2* st1   = (float2*)(ws + 84*MB + 16384);
  float2* st2   = (float2*)(ws + 84*MB + 16384 + 64);

  const int M = B_*T_;
  dim3 blk(256);

  k_wt<<<dim3(FFD/32, D_/32), blk, 0, stream>>>(ff1_w1, ff1w1t, D_, FFD);
  k_wt<<<dim3(D_/32, FFD/32), blk, 0, stream>>>(ff1_w2, ff1w2t, FFD, D_);
  k_wt<<<dim3(1536/32, D_/32), blk, 0, stream>>>(qkv_w, qkvt, D_, 1536);
  k_wt<<<dim3(D_/32, D_/32), blk, 0, stream>>>(out_w, outt, D_, D_);
  k_wt_glu<<<dim3(1024/32, D_/32), blk, 0, stream>>>(pw1_w, pw1t, D_, 1024);
  k_wt<<<dim3(D_/32, D_/32), blk, 0, stream>>>(pw2_w, pw2t, D_, D_);
  k_wt<<<dim3(FFD/32, D_/32), blk, 0, stream>>>(ff2_w1, ff2w1t, D_, FFD);
  k_wt<<<dim3(D_/32, FFD/32), blk, 0, stream>>>(ff2_w2, ff2w2t, FFD, D_);
  k_rb<<<dim3(64), blk, 0, stream>>>(rel_embed, rbg);
  k_dwt<<<dim3(62), blk, 0, stream>>>(dw_w, wdt);

  k_xin<<<dim3(T_/32, D_/32, B_), blk, 0, stream>>>(x, s0f, s0b);

  // FFN1: h1 = gelu(s0 @ W1)  [BM=128, grid 512]
  k_gemm_mfma<128><<<dim3(FFD/128, M/128), blk, 0, stream>>>(s0b, ff1w1t, ff1_b1, nullptr, 0.f,
      nullptr, h1b, nullptr, nullptr, nullptr, nullptr, nullptr, nullptr, M, FFD, D_, 0, 1);
  // FFN1-2: split-K=2 (grid 512) + combine
  k_gemm_mfma<64><<<dim3(D_/128, M/64, 2), blk, 0, stream>>>(h1b, ff1w2t, nullptr, nullptr, 0.f,
      nullptr, nullptr, nullptr, nullptr, nullptr, nullptr, nullptr, PK1, M, D_, FFD, 1024, 0);
  k_combine<<<dim3((M*128)/256), blk, 0, stream>>>((const float4*)PK1, ff1_b2, (const float4*)s0f, 0.5f,
      (float4*)Sf, Sb);
  // QKV  [BM=64, grid 768]
  k_gemm_mfma<64><<<dim3(1536/128, M/64), blk, 0, stream>>>(Sb, qkvt, qkv_b, nullptr, 0.f,
      nullptr, nullptr, qbb, kbb, vbb, nullptr, nullptr, nullptr, M, 1536, D_, 0, 0);
  k_vt<<<dim3(B_*H_*16), blk, 0, stream>>>(vbb, vtb);
  k_attn3<<<dim3(B_*H_*16), blk, 0, stream>>>(qbb, kbb, vtb, rbg, gate_u, gate_w, gate_scale, attb);
  // out proj + residual + GN1 partials  [BM=64, grid 256]
  k_gemm_mfma<64><<<dim3(D_/128, M/64), blk, 0, stream>>>(attb, outt, out_b, Sf, 1.f,
      S2f, nullptr, nullptr, nullptr, nullptr, nullptr, part1, nullptr, M, D_, D_, 0, 0);
  k_gn_final<<<dim3(B_), dim3(64), 0, stream>>>(part1, st1, 64);
  k_gn_apply<<<dim3((M*D_)/256), blk, 0, stream>>>(S2f, st1, gn1_g, gn1_b, gn1b, 0);
  // pw1 + fused GLU  [BM=64, grid 512]
  k_gemm_mfma<64><<<dim3(1024/128, M/64), blk, 0, stream>>>(gn1b, pw1t, pw1_b, nullptr, 0.f,
      nullptr, nullptr, nullptr, nullptr, nullptr, glub, nullptr, nullptr, M, 1024, D_, 0, 0);
  // depthwise conv + GN2 partials
  k_dwconv2<<<dim3(2, T_/16, B_), blk, 0, stream>>>(glub, wdt, dw_b, dcf, part2);
  k_gn_final<<<dim3(B_), dim3(64), 0, stream>>>(part2, st2, 128);
  k_gn_apply<<<dim3((M*D_)/256), blk, 0, stream>>>(dcf, st2, gn2_g, gn2_b, gn2b, 1);
  // pw2 + residual  [BM=64, grid 256]
  k_gemm_mfma<64><<<dim3(D_/128, M/64), blk, 0, stream>>>(gn2b, pw2t, pw2_b, S2f, 1.f,
      S3f, S3b, nullptr, nullptr, nullptr, nullptr, nullptr, nullptr, M, D_, D_, 0, 0);
  // FFN2
  k_gemm_mfma<128><<<dim3(FFD/128, M/128), blk, 0, stream>>>(S3b, ff2w1t, ff2_b1, nullptr, 0.f,
      nullptr, h3b, nullptr, nullptr, nullptr, nullptr, nullptr, nullptr, M, FFD, D_, 0, 1);
  k_gemm_mfma<64><<<dim3(D_/128, M/64, 2), blk, 0, stream>>>(h3b, ff2w2t, nullptr, nullptr, 0.f,
      nullptr, nullptr, nullptr, nullptr, nullptr, nullptr, nullptr, PK2, M, D_, FFD, 1024, 0);
  k_combine<<<dim3((M*128)/256), blk, 0, stream>>>((const float4*)PK2, ff2_b2, (const float4*)S3f, 0.5f,
      (float4*)Sout, nullptr);
  k_transpose_out<<<dim3(D_/32, T_/32, B_), blk, 0, stream>>>(Sout, (float*)d_out);
}

// Round 13
// 399.296 us; speedup vs baseline: 10.4853x; 1.1002x over previous
//
#include <hip/hip_runtime.h>
#include <hip/hip_bf16.h>
#include <math.h>

#define B_ 4
#define D_ 512
#define T_ 1024
#define H_ 8
#define FFD 2048

typedef unsigned short u16;
typedef short s16x8 __attribute__((ext_vector_type(8)));
typedef float f32x4 __attribute__((ext_vector_type(4)));

__device__ inline float sigm(float x){ return 1.f/(1.f+expf(-x)); }
__device__ inline float gelu_exact(float x){ return 0.5f*x*(1.f+erff(x*0.70710678118654752440f)); }
__device__ inline u16 f2b(float f){
  __hip_bfloat16 h = __float2bfloat16(f);
  return *reinterpret_cast<u16*>(&h);
}
__device__ inline float b2f(u16 u){ return __uint_as_float(((unsigned)u)<<16); }

__device__ inline void gl_lds16(const void* g, void* l) {
  __builtin_amdgcn_global_load_lds(
      (const __attribute__((address_space(1))) void*)g,
      (__attribute__((address_space(3))) void*)l, 16, 0, 0);
}

// ================= fused prep =================
__device__ void wt_tile(const float* __restrict__ w, u16* __restrict__ wt,
                        int K, int N, int nxb, int kyb, float (*tile)[33], bool glu) {
  int n0 = nxb*32, k0 = kyb*32;
  int c = threadIdx.x & 31, r = threadIdx.x >> 5;
  for (int rr = r; rr < 32; rr += 8)
    tile[rr][c] = w[(size_t)(k0+rr)*N + n0 + c];
  __syncthreads();
  for (int rr = r; rr < 32; rr += 8) {
    int nr = n0 + rr;
    int np = glu ? ((nr < 512) ? nr*2 : (nr-512)*2 + 1) : nr;
    wt[(size_t)np*K + k0 + c] = f2b(tile[c][rr]);
  }
}

__device__ void xin_tile(const float* __restrict__ x, float* __restrict__ sf, u16* __restrict__ sb,
                         int tb, int db, int bb, float (*tile)[33]) {
  int d0 = db*32, t0 = tb*32;
  int c = threadIdx.x & 31, r = threadIdx.x >> 5;
  for (int rr = r; rr < 32; rr += 8)
    tile[rr][c] = x[((size_t)(bb*D_ + d0 + rr))*T_ + t0 + c];
  __syncthreads();
  for (int rr = r; rr < 32; rr += 8) {
    float v = tile[c][rr];
    size_t o = ((size_t)(bb*T_ + t0 + rr))*D_ + d0 + c;
    sf[o] = v; sb[o] = f2b(v);
  }
}

__global__ __launch_bounds__(256) void k_prep(
    const float* __restrict__ x,
    const float* __restrict__ ff1_w1, const float* __restrict__ ff1_w2,
    const float* __restrict__ qkv_w, const float* __restrict__ out_w,
    const float* __restrict__ pw1_w, const float* __restrict__ pw2_w,
    const float* __restrict__ ff2_w1, const float* __restrict__ ff2_w2,
    const float* __restrict__ rel_embed, const float* __restrict__ dw_w,
    float* __restrict__ s0f, u16* __restrict__ s0b,
    u16* ff1w1t, u16* ff1w2t, u16* qkvt, u16* outt, u16* pw1t, u16* pw2t,
    u16* ff2w1t, u16* ff2w2t, float* __restrict__ rbg, float* __restrict__ wdt)
{
  __shared__ float tile[32][33];
  int bid = blockIdx.x;
  if (bid < 1024) { wt_tile(ff1_w1, ff1w1t, 512, 2048, bid%64, bid/64, tile, false); return; }
  bid -= 1024;
  if (bid < 1024) { wt_tile(ff1_w2, ff1w2t, 2048, 512, bid%16, bid/16, tile, false); return; }
  bid -= 1024;
  if (bid < 768)  { wt_tile(qkv_w, qkvt, 512, 1536, bid%48, bid/48, tile, false); return; }
  bid -= 768;
  if (bid < 256)  { wt_tile(out_w, outt, 512, 512, bid%16, bid/16, tile, false); return; }
  bid -= 256;
  if (bid < 512)  { wt_tile(pw1_w, pw1t, 512, 1024, bid%32, bid/32, tile, true); return; }
  bid -= 512;
  if (bid < 256)  { wt_tile(pw2_w, pw2t, 512, 512, bid%16, bid/16, tile, false); return; }
  bid -= 256;
  if (bid < 1024) { wt_tile(ff2_w1, ff2w1t, 512, 2048, bid%64, bid/64, tile, false); return; }
  bid -= 1024;
  if (bid < 1024) { wt_tile(ff2_w2, ff2w2t, 2048, 512, bid%16, bid/16, tile, false); return; }
  bid -= 1024;
  if (bid < 64) {   // Toeplitz bias table
    int idx = bid*256 + threadIdx.x;
    int h = idx >> 11, j = idx & 2047;
    if (j >= 2047) { rbg[idx] = 0.f; return; }
    int rel = j - 1023;
    int sign = rel >= 0 ? 1 : 0;
    int a = rel >= 0 ? rel : -rel;
    int bkt;
    if (a < 80) bkt = a;
    else {
      float lr = logf((float)a / 80.f) / 2.30258509299404568402f;
      int lp = 80 + (int)(lr * 80.f);
      bkt = lp < 159 ? lp : 159;
    }
    bkt += sign*160;
    rbg[idx] = rel_embed[bkt*H_ + h];
    return;
  }
  bid -= 64;
  if (bid < 62) {   // dw weight transpose
    int idx = bid*256 + threadIdx.x;
    if (idx < 31*512) {
      int k = idx >> 9, d = idx & 511;
      wdt[idx] = dw_w[d*31 + k];
    }
    return;
  }
  bid -= 62;
  // x transpose: 2048 blocks
  int tb = bid & 31, db = (bid >> 5) & 15, bb = bid >> 9;
  xin_tile(x, s0f, s0b, tb, db, bb, tile);
}

// ---- final: s f32 [B,T,D] -> out f32 [B,D,T]
__global__ __launch_bounds__(256) void k_transpose_out(const float* __restrict__ s, float* __restrict__ o) {
  __shared__ float tile[32][33];
  int b = blockIdx.z;
  int t0 = blockIdx.y * 32;
  int d0 = blockIdx.x * 32;
  int c = threadIdx.x & 31, r = threadIdx.x >> 5;
  for (int rr = r; rr < 32; rr += 8)
    tile[rr][c] = s[((size_t)(b*T_ + t0 + rr))*D_ + d0 + c];
  __syncthreads();
  for (int rr = r; rr < 32; rr += 8)
    o[((size_t)(b*D_ + d0 + rr))*T_ + t0 + c] = tile[c][rr];
}

// ================= MFMA GEMM, BM x BN tile, 4 waves (2x2), BK=64 =================
template<int BM, int BN>
__global__ __launch_bounds__(256) void k_gemm_mfma(
    const u16* __restrict__ A, const u16* __restrict__ Wt,
    const float* __restrict__ bias, const float* __restrict__ res, float rscale,
    float* __restrict__ outf, u16* __restrict__ outb,
    u16* __restrict__ qd, u16* __restrict__ kd, u16* __restrict__ vd,
    u16* __restrict__ glub, float2* __restrict__ gnp, float* __restrict__ partf,
    int M, int N, int K, int kLen, int act)
{
  constexpr int MFR = BM/32, NFR = BN/32;
  __shared__ u16 Ab[BM*64];
  __shared__ u16 Bb[BN*64];
  int tid = threadIdx.x;
  int w = tid >> 6, lane = tid & 63;
  int lr = lane & 15, lk = lane >> 4;
  int wm = w >> 1, wn = w & 1;
  int m0 = blockIdx.y * BM, n0 = blockIdx.x * BN;
  int kbeg = partf ? blockIdx.z * kLen : 0;
  int kend = partf ? kbeg + kLen : K;
  f32x4 acc[MFR][NFR] = {};

  for (int kt = kbeg; kt < kend; kt += 64) {
    #pragma unroll
    for (int i = 0; i < MFR; ++i) {
      int slot = (w*MFR + i)*64 + lane;
      int r = slot >> 3, sc = slot & 7;
      int cc = sc ^ (r & 7);
      gl_lds16(A + (size_t)(m0 + r)*K + kt + cc*8, (char*)Ab + (size_t)(w*MFR+i)*1024);
    }
    #pragma unroll
    for (int i = 0; i < NFR; ++i) {
      int slot = (w*NFR + i)*64 + lane;
      int r = slot >> 3, sc = slot & 7;
      int cc = sc ^ (r & 7);
      gl_lds16(Wt + (size_t)(n0 + r)*K + kt + cc*8, (char*)Bb + (size_t)(w*NFR+i)*1024);
    }
    __syncthreads();
    #pragma unroll
    for (int ks = 0; ks < 2; ++ks) {
      s16x8 af[MFR], bfv[NFR];
      #pragma unroll
      for (int m = 0; m < MFR; ++m) {
        int r = wm*(BM/2) + m*16 + lr;
        int sl = (ks*4 + lk) ^ (r & 7);
        af[m] = *(const s16x8*)(Ab + r*64 + sl*8);
      }
      #pragma unroll
      for (int n = 0; n < NFR; ++n) {
        int r = wn*(BN/2) + n*16 + lr;
        int sl = (ks*4 + lk) ^ (r & 7);
        bfv[n] = *(const s16x8*)(Bb + r*64 + sl*8);
      }
      #pragma unroll
      for (int m = 0; m < MFR; ++m)
        #pragma unroll
        for (int n = 0; n < NFR; ++n)
          acc[m][n] = __builtin_amdgcn_mfma_f32_16x16x32_bf16(af[m], bfv[n], acc[m][n], 0, 0, 0);
    }
    __syncthreads();
  }

  if (partf) {
    float* pp = partf + (size_t)blockIdx.z * M * N;
    #pragma unroll
    for (int m = 0; m < MFR; ++m)
      #pragma unroll
      for (int n = 0; n < NFR; ++n)
        #pragma unroll
        for (int r2 = 0; r2 < 4; ++r2) {
          int row = m0 + wm*(BM/2) + m*16 + lk*4 + r2;
          int col = n0 + wn*(BN/2) + n*16 + lr;
          pp[(size_t)row*N + col] = acc[m][n][r2];
        }
    return;
  }

  float psum = 0.f, psq = 0.f;
  #pragma unroll
  for (int m = 0; m < MFR; ++m) {
    #pragma unroll
    for (int n = 0; n < NFR; ++n) {
      #pragma unroll
      for (int r2 = 0; r2 < 4; ++r2) {
        int row = m0 + wm*(BM/2) + m*16 + lk*4 + r2;
        int col = n0 + wn*(BN/2) + n*16 + lr;
        if (glub) {
          float vv = acc[m][n][r2] + bias[(col&1)*512 + (col>>1)];
          float pv = __shfl_xor(vv, 1);
          if ((col & 1) == 0)
            glub[(size_t)row*512 + (col>>1)] = f2b(vv * sigm(pv));
        } else {
          float vv = acc[m][n][r2] + bias[col];
          if (act) vv = gelu_exact(vv);
          size_t off = (size_t)row * N + col;
          if (res)  vv = res[off] + rscale * vv;
          if (outf) outf[off] = vv;
          if (outb) outb[off] = f2b(vv);
          if (qd) {
            int part = col >> 9, h = (col >> 6) & 7, dh = col & 63;
            int b = row >> 10, t = row & (T_-1);
            u16* dst = part == 0 ? qd : (part == 1 ? kd : vd);
            dst[(((size_t)(b*H_ + h))*T_ + t)*64 + dh] = f2b(vv);
          }
          psum += vv; psq += vv*vv;
        }
      }
    }
  }
  if (gnp) {
    float* r1 = (float*)Ab;
    float* r2s = (float*)Bb;
    __syncthreads();
    r1[tid] = psum; r2s[tid] = psq;
    __syncthreads();
    for (int off = 128; off; off >>= 1) {
      if (tid < off) { r1[tid] += r1[tid+off]; r2s[tid] += r2s[tid+off]; }
      __syncthreads();
    }
    if (tid == 0) {
      int bb = m0 >> 10;
      int mpb = 1024/BM, nb = N/BN;
      int mloc = (m0/BM) & (mpb - 1);
      gnp[bb*mpb*nb + mloc*nb + n0/BN] = make_float2(r1[0], r2s[0]);
    }
  }
}

// ---- split-K combine: out = res + rscale*(p0+p1+bias), f32 + optional bf16
__global__ __launch_bounds__(256) void k_combine(
    const float4* __restrict__ p, const float* __restrict__ bias,
    const float4* __restrict__ res, float rscale,
    float4* __restrict__ outf, u16* __restrict__ outb)
{
  size_t i = (size_t)blockIdx.x*256 + threadIdx.x;   // over M*128 float4s
  int c4 = (i & 127) << 2;
  float4 a = p[i];
  float4 b = p[i + (size_t)(B_*T_)*128];
  float4 bs = *(const float4*)(bias + c4);
  float4 r = res[i];
  float4 v;
  v.x = r.x + rscale*(a.x + b.x + bs.x);
  v.y = r.y + rscale*(a.y + b.y + bs.y);
  v.z = r.z + rscale*(a.z + b.z + bs.z);
  v.w = r.w + rscale*(a.w + b.w + bs.w);
  if (outf) outf[i] = v;
  if (outb) {
    ushort4 u; u.x = f2b(v.x); u.y = f2b(v.y); u.z = f2b(v.z); u.w = f2b(v.w);
    *(ushort4*)(outb + i*4) = u;
  }
}

// ---- V transpose: vb bf16 [B,H,T,64] -> vtb bf16 [B,H,64,T]
__global__ __launch_bounds__(256) void k_vt(const u16* __restrict__ vb, u16* __restrict__ vtb) {
  __shared__ u16 tl[64][65];
  int blk = blockIdx.x;
  int tt0 = (blk & 15) * 64;
  size_t bh = (size_t)(blk >> 4);
  int tid = threadIdx.x;
  #pragma unroll
  for (int i = 0; i < 4; ++i) {
    int idx = i*256 + tid;
    int t = idx >> 4, d0 = (idx & 15) * 4;
    *(ushort4*)&tl[t][d0] = *(const ushort4*)(vb + (bh*T_ + tt0 + t)*64 + d0);
  }
  __syncthreads();
  #pragma unroll
  for (int i = 0; i < 4; ++i) {
    int idx = i*256 + tid;
    int dh = idx >> 4, t4 = (idx & 15) * 4;
    ushort4 o;
    o.x = tl[t4+0][dh]; o.y = tl[t4+1][dh]; o.z = tl[t4+2][dh]; o.w = tl[t4+3][dh];
    *(ushort4*)(vtb + (bh*64 + dh)*T_ + tt0 + t4) = o;
  }
}

// ---- MFMA flash attention
__global__ __launch_bounds__(256) void k_attn3(
    const u16* __restrict__ qb, const u16* __restrict__ kb, const u16* __restrict__ vtb,
    const float* __restrict__ rbg,
    const float* __restrict__ gu, const float* __restrict__ gw, const float* __restrict__ gs,
    u16* __restrict__ outb)
{
  __shared__ u16 Kl[64*64];
  __shared__ u16 Vtl[64*64];
  __shared__ u16 Pl[64*64];
  __shared__ float rb[2048];
  __shared__ float cf[64];
  int blk = blockIdx.x;
  int qt = blk & 15;
  int h  = (blk >> 4) & 7;
  int b  = blk >> 7;
  int tid = threadIdx.x;
  int w = tid >> 6, lane = tid & 63;
  int lr = lane & 15, lk = lane >> 4;
  int g = lane >> 4;
  int t0 = qt * 64;
  size_t bh = (size_t)(b*H_ + h);

  for (int j = tid; j < 2048; j += 256) rb[j] = rbg[h*2048 + j];
  if (tid < 64) {
    const u16* qrow = qb + (bh*T_ + t0 + tid)*64;
    float vu = 0.f, vw = 0.f;
    for (int kk2 = 0; kk2 < 64; ++kk2) {
      float qv = b2f(qrow[kk2]);
      vu += qv * gu[h*64+kk2];
      vw += qv * gw[h*64+kk2];
    }
    float g1 = sigm(vu), g2 = sigm(vw);
    cf[tid] = 1.f + g1 + (1.f-g1)*gs[h]*g2;
  }
  const u16* qbase = qb + (bh*T_ + t0 + w*16 + lr)*64;
  s16x8 qa0 = *(const s16x8*)(qbase + lk*8);
  s16x8 qa1 = *(const s16x8*)(qbase + 32 + lk*8);

  f32x4 O[4] = {};
  float mcur[4] = {-1e30f,-1e30f,-1e30f,-1e30f};
  float lsum[4] = {0.f,0.f,0.f,0.f};
  const f32x4 zero = {0.f,0.f,0.f,0.f};
  __syncthreads();

  for (int kt = 0; kt < 16; ++kt) {
    #pragma unroll
    for (int i = 0; i < 2; ++i) {
      int slot = (i*4 + w)*64 + lane;
      int r = slot >> 3, scc = slot & 7;
      int cc = scc ^ (r & 7);
      gl_lds16(kb  + (bh*T_ + kt*64 + r)*64 + cc*8, (char*)Kl  + (i*4+w)*1024);
      gl_lds16(vtb + (bh*64 + r)*T_ + kt*64 + cc*8, (char*)Vtl + (i*4+w)*1024);
    }
    __syncthreads();
    f32x4 sc[4];
    #pragma unroll
    for (int n = 0; n < 4; ++n) {
      int row = n*16 + lr;
      int c0 = (0*4 + lk) ^ (row & 7);
      int c1 = (1*4 + lk) ^ (row & 7);
      s16x8 kb0 = *(const s16x8*)(Kl + row*64 + c0*8);
      s16x8 kb1 = *(const s16x8*)(Kl + row*64 + c1*8);
      f32x4 t = __builtin_amdgcn_mfma_f32_16x16x32_bf16(qa0, kb0, zero, 0, 0, 0);
      sc[n]   = __builtin_amdgcn_mfma_f32_16x16x32_bf16(qa1, kb1, t, 0, 0, 0);
    }
    float tmax[4];
    #pragma unroll
    for (int r2 = 0; r2 < 4; ++r2) {
      int q_local = w*16 + g*4 + r2;
      float cfv = cf[q_local];
      int qabs = t0 + q_local;
      float mx = -1e30f;
      #pragma unroll
      for (int n = 0; n < 4; ++n) {
        int sabs = kt*64 + n*16 + lr;
        float v = sc[n][r2]*0.125f + cfv * rb[sabs - qabs + 1023];
        sc[n][r2] = v;
        mx = fmaxf(mx, v);
      }
      tmax[r2] = mx;
    }
    #pragma unroll
    for (int mk = 1; mk < 16; mk <<= 1)
      #pragma unroll
      for (int r2 = 0; r2 < 4; ++r2)
        tmax[r2] = fmaxf(tmax[r2], __shfl_xor(tmax[r2], mk));
    float scl[4], psum[4];
    #pragma unroll
    for (int r2 = 0; r2 < 4; ++r2) {
      float mnew = fmaxf(mcur[r2], tmax[r2]);
      scl[r2] = __expf(mcur[r2] - mnew);
      mcur[r2] = mnew;
      int q_local = w*16 + g*4 + r2;
      float ps = 0.f;
      #pragma unroll
      for (int n = 0; n < 4; ++n) {
        float e = __expf(sc[n][r2] - mnew);
        ps += e;
        int s_local = n*16 + lr;
        Pl[q_local*64 + (((s_local>>3) ^ (q_local&7))<<3) + (s_local&7)] = f2b(e);
      }
      psum[r2] = ps;
    }
    #pragma unroll
    for (int mk = 1; mk < 16; mk <<= 1)
      #pragma unroll
      for (int r2 = 0; r2 < 4; ++r2)
        psum[r2] += __shfl_xor(psum[r2], mk);
    #pragma unroll
    for (int r2 = 0; r2 < 4; ++r2) lsum[r2] = lsum[r2]*scl[r2] + psum[r2];
    #pragma unroll
    for (int n = 0; n < 4; ++n)
      #pragma unroll
      for (int r2 = 0; r2 < 4; ++r2)
        O[n][r2] *= scl[r2];
    __syncthreads();
    int qrow = w*16 + lr;
    int pc0 = (0*4 + lk) ^ (qrow & 7), pc1 = (1*4 + lk) ^ (qrow & 7);
    s16x8 pa0 = *(const s16x8*)(Pl + qrow*64 + pc0*8);
    s16x8 pa1 = *(const s16x8*)(Pl + qrow*64 + pc1*8);
    #pragma unroll
    for (int n = 0; n < 4; ++n) {
      int dh = n*16 + lr;
      int c0 = (0*4 + lk) ^ (dh & 7), c1 = (1*4 + lk) ^ (dh & 7);
      s16x8 vb0 = *(const s16x8*)(Vtl + dh*64 + c0*8);
      s16x8 vb1 = *(const s16x8*)(Vtl + dh*64 + c1*8);
      O[n] = __builtin_amdgcn_mfma_f32_16x16x32_bf16(pa0, vb0, O[n], 0, 0, 0);
      O[n] = __builtin_amdgcn_mfma_f32_16x16x32_bf16(pa1, vb1, O[n], 0, 0, 0);
    }
    __syncthreads();
  }
  float inv[4];
  #pragma unroll
  for (int r2 = 0; r2 < 4; ++r2) inv[r2] = 1.f / lsum[r2];
  #pragma unroll
  for (int n = 0; n < 4; ++n)
    #pragma unroll
    for (int r2 = 0; r2 < 4; ++r2) {
      int q = t0 + w*16 + g*4 + r2;
      int dh = n*16 + lr;
      outb[((size_t)(b*T_) + q)*512 + h*64 + dh] = f2b(O[n][r2]*inv[r2]);
    }
}

// ---- depthwise conv: thread = 1 channel x 16 outputs, register sliding window
__global__ __launch_bounds__(256) void k_dwconv2(
    const u16* __restrict__ g, const float* __restrict__ wdt,
    const float* __restrict__ bias, float* __restrict__ o, float2* __restrict__ part)
{
  int b = blockIdx.z, tg = blockIdx.y;
  int ch = blockIdx.x*256 + threadIdx.x;
  int t0 = tg*16;
  float wk[31];
  #pragma unroll
  for (int k = 0; k < 31; ++k) wk[k] = wdt[k*512 + ch];
  float win[46];
  const u16* gb = g + ((size_t)b*T_)*512 + ch;
  #pragma unroll
  for (int j = 0; j < 46; ++j) {
    int tt = t0 + j - 15;
    win[j] = (tt >= 0 && tt < T_) ? b2f(gb[(size_t)tt*512]) : 0.f;
  }
  float bv = bias[ch];
  float bsum = 0.f, bsq = 0.f;
  float* ob = o + ((size_t)b*T_ + t0)*512 + ch;
  #pragma unroll
  for (int j = 0; j < 16; ++j) {
    float acc = bv;
    #pragma unroll
    for (int k = 0; k < 31; ++k) acc += win[j+k]*wk[k];
    ob[(size_t)j*512] = acc;
    bsum += acc; bsq += acc*acc;
  }
  __shared__ float rs[256], rq[256];
  rs[threadIdx.x] = bsum; rq[threadIdx.x] = bsq; __syncthreads();
  for (int off = 128; off; off >>= 1) {
    if (threadIdx.x < off) { rs[threadIdx.x] += rs[threadIdx.x+off]; rq[threadIdx.x] += rq[threadIdx.x+off]; }
    __syncthreads();
  }
  if (threadIdx.x == 0) part[b*128 + tg*2 + blockIdx.x] = make_float2(rs[0], rq[0]);
}

// ---- GN apply with inline partial-reduction (replaces gn_final + gn_apply)
__global__ __launch_bounds__(256) void k_gn_apply(
    const float* __restrict__ x, const float2* __restrict__ part, int np,
    const float* __restrict__ g, const float* __restrict__ bta,
    u16* __restrict__ o, int silu_flag)
{
  __shared__ float rs[256], rq[256];
  __shared__ float2 stat;
  size_t idx = (size_t)blockIdx.x*256 + threadIdx.x;
  int b = (int)(idx >> 19);
  float s = 0.f, s2 = 0.f;
  for (int i = threadIdx.x; i < np; i += 256) {
    float2 p = part[b*np + i]; s += p.x; s2 += p.y;
  }
  rs[threadIdx.x] = s; rq[threadIdx.x] = s2; __syncthreads();
  for (int off = 128; off; off >>= 1) {
    if (threadIdx.x < off) { rs[threadIdx.x] += rs[threadIdx.x+off]; rq[threadIdx.x] += rq[threadIdx.x+off]; }
    __syncthreads();
  }
  if (threadIdx.x == 0) {
    float cnt = (float)(D_*T_);
    float mean = rs[0]/cnt;
    float var = rq[0]/cnt - mean*mean;
    stat = make_float2(mean, rsqrtf(var + 1e-5f));
  }
  __syncthreads();
  int dd = idx & (D_-1);
  float v = (x[idx]-stat.x)*stat.y*g[dd] + bta[dd];
  if (silu_flag) v = v*sigm(v);
  o[idx] = f2b(v);
}

extern "C" void kernel_launch(void* const* d_in, const int* in_sizes, int n_in,
                              void* d_out, int out_size, void* d_ws, size_t ws_size,
                              hipStream_t stream)
{
  const float* x      = (const float*)d_in[0];
  const float* ff1_w1 = (const float*)d_in[1];
  const float* ff1_b1 = (const float*)d_in[2];
  const float* ff1_w2 = (const float*)d_in[3];
  const float* ff1_b2 = (const float*)d_in[4];
  const float* qkv_w  = (const float*)d_in[5];
  const float* qkv_b  = (const float*)d_in[6];
  const float* out_w  = (const float*)d_in[7];
  const float* out_b  = (const float*)d_in[8];
  const float* gn1_g  = (const float*)d_in[9];
  const float* gn1_b  = (const float*)d_in[10];
  const float* pw1_w  = (const float*)d_in[11];
  const float* pw1_b  = (const float*)d_in[12];
  const float* dw_w   = (const float*)d_in[13];
  const float* dw_b   = (const float*)d_in[14];
  const float* gn2_g  = (const float*)d_in[15];
  const float* gn2_b  = (const float*)d_in[16];
  const float* pw2_w  = (const float*)d_in[17];
  const float* pw2_b  = (const float*)d_in[18];
  const float* ff2_w1 = (const float*)d_in[19];
  const float* ff2_b1 = (const float*)d_in[20];
  const float* ff2_w2 = (const float*)d_in[21];
  const float* ff2_b2 = (const float*)d_in[22];
  const float* rel_embed = (const float*)d_in[23];
  const float* gate_u = (const float*)d_in[24];
  const float* gate_w = (const float*)d_in[25];
  const float* gate_scale = (const float*)d_in[26];

  char* ws = (char*)d_ws;
  const size_t MB = (size_t)1 << 20;
  float* s0f  = (float*)(ws + 0*MB);
  u16*   s0b  = (u16*)  (ws + 8*MB);
  u16*   h1b  = (u16*)  (ws + 12*MB);
  float* Sf   = (float*)(ws + 28*MB);
  u16*   Sb   = (u16*)  (ws + 36*MB);
  u16*   qbb  = (u16*)  (ws + 40*MB);
  u16*   kbb  = (u16*)  (ws + 44*MB);
  u16*   vbb  = (u16*)  (ws + 48*MB);
  u16*   vtb  = (u16*)  (ws + 52*MB);
  // aliases
  float* S2f  = (float*)(ws + 0*MB);
  u16*   attb = (u16*)  (ws + 8*MB);
  u16*   gn1b = (u16*)  (ws + 36*MB);
  u16*   glub = (u16*)  (ws + 56*MB);   // [M,512] bf16
  float* dcf  = (float*)(ws + 28*MB);
  u16*   gn2b = (u16*)  (ws + 36*MB);
  float* S3f  = (float*)(ws + 40*MB);
  u16*   S3b  = (u16*)  (ws + 48*MB);
  u16*   h3b  = (u16*)  (ws + 12*MB);
  float* Sout = (float*)(ws + 28*MB);
  float* PK1  = (float*)(ws + 40*MB);   // 16MB split-K partials (FFN1-2)
  float* PK2  = (float*)(ws + 48*MB);   // 16MB split-K partials (FFN2-2)
  // weights bf16
  u16* ff1w1t = (u16*)(ws + 64*MB);
  u16* ff1w2t = (u16*)(ws + 66*MB);
  u16* qkvt   = (u16*)(ws + 68*MB);
  u16* outt   = (u16*)(ws + 70*MB);
  u16* pw1t   = (u16*)(ws + 72*MB);
  u16* pw2t   = (u16*)(ws + 74*MB);
  u16* ff2w1t = (u16*)(ws + 76*MB);
  u16* ff2w2t = (u16*)(ws + 78*MB);
  float* rbg  = (float*)(ws + 80*MB);
  float* wdt  = (float*)(ws + 81*MB);
  float2* part1 = (float2*)(ws + 84*MB);
  float2* part2 = (float2*)(ws + 84*MB + 8192);

  const int M = B_*T_;
  dim3 blk(256);

  // single fused prep (weights + tables + x transpose)
  k_prep<<<dim3(8062), blk, 0, stream>>>(x, ff1_w1, ff1_w2, qkv_w, out_w, pw1_w, pw2_w,
      ff2_w1, ff2_w2, rel_embed, dw_w, s0f, s0b,
      ff1w1t, ff1w2t, qkvt, outt, pw1t, pw2t, ff2w1t, ff2w2t, rbg, wdt);

  // FFN1: h1 = gelu(s0 @ W1)  [128x128, grid 512]
  k_gemm_mfma<128,128><<<dim3(FFD/128, M/128), blk, 0, stream>>>(s0b, ff1w1t, ff1_b1, nullptr, 0.f,
      nullptr, h1b, nullptr, nullptr, nullptr, nullptr, nullptr, nullptr, M, FFD, D_, 0, 1);
  // FFN1-2: split-K=2 [64x64, grid 1024] + combine
  k_gemm_mfma<64,64><<<dim3(D_/64, M/64, 2), blk, 0, stream>>>(h1b, ff1w2t, nullptr, nullptr, 0.f,
      nullptr, nullptr, nullptr, nullptr, nullptr, nullptr, nullptr, PK1, M, D_, FFD, 1024, 0);
  k_combine<<<dim3((M*128)/256), blk, 0, stream>>>((const float4*)PK1, ff1_b2, (const float4*)s0f, 0.5f,
      (float4*)Sf, Sb);
  // QKV  [64x64, grid 1536]
  k_gemm_mfma<64,64><<<dim3(1536/64, M/64), blk, 0, stream>>>(Sb, qkvt, qkv_b, nullptr, 0.f,
      nullptr, nullptr, qbb, kbb, vbb, nullptr, nullptr, nullptr, M, 1536, D_, 0, 0);
  k_vt<<<dim3(B_*H_*16), blk, 0, stream>>>(vbb, vtb);
  k_attn3<<<dim3(B_*H_*16), blk, 0, stream>>>(qbb, kbb, vtb, rbg, gate_u, gate_w, gate_scale, attb);
  // out proj + residual + GN1 partials  [64x64, grid 512]
  k_gemm_mfma<64,64><<<dim3(D_/64, M/64), blk, 0, stream>>>(attb, outt, out_b, Sf, 1.f,
      S2f, nullptr, nullptr, nullptr, nullptr, nullptr, part1, nullptr, M, D_, D_, 0, 0);
  k_gn_apply<<<dim3((M*D_)/256), blk, 0, stream>>>(S2f, part1, 128, gn1_g, gn1_b, gn1b, 0);
  // pw1 + fused GLU  [64x64, grid 1024]
  k_gemm_mfma<64,64><<<dim3(1024/64, M/64), blk, 0, stream>>>(gn1b, pw1t, pw1_b, nullptr, 0.f,
      nullptr, nullptr, nullptr, nullptr, nullptr, glub, nullptr, nullptr, M, 1024, D_, 0, 0);
  // depthwise conv + GN2 partials
  k_dwconv2<<<dim3(2, T_/16, B_), blk, 0, stream>>>(glub, wdt, dw_b, dcf, part2);
  k_gn_apply<<<dim3((M*D_)/256), blk, 0, stream>>>(dcf, part2, 128, gn2_g, gn2_b, gn2b, 1);
  // pw2 + residual  [64x64, grid 512]
  k_gemm_mfma<64,64><<<dim3(D_/64, M/64), blk, 0, stream>>>(gn2b, pw2t, pw2_b, S2f, 1.f,
      S3f, S3b, nullptr, nullptr, nullptr, nullptr, nullptr, nullptr, M, D_, D_, 0, 0);
  // FFN2
  k_gemm_mfma<128,128><<<dim3(FFD/128, M/128), blk, 0, stream>>>(S3b, ff2w1t, ff2_b1, nullptr, 0.f,
      nullptr, h3b, nullptr, nullptr, nullptr, nullptr, nullptr, nullptr, M, FFD, D_, 0, 1);
  k_gemm_mfma<64,64><<<dim3(D_/64, M/64, 2), blk, 0, stream>>>(h3b, ff2w2t, nullptr, nullptr, 0.f,
      nullptr, nullptr, nullptr, nullptr, nullptr, nullptr, nullptr, PK2, M, D_, FFD, 1024, 0);
  k_combine<<<dim3((M*128)/256), blk, 0, stream>>>((const float4*)PK2, ff2_b2, (const float4*)S3f, 0.5f,
      (float4*)Sout, nullptr);
  k_transpose_out<<<dim3(D_/32, T_/32, B_), blk, 0, stream>>>(Sout, (float*)d_out);
}